// Round 1
// baseline (453.525 us; speedup 1.0000x reference)
//
#include <hip/hip_runtime.h>
#include <cfloat>
#include <math.h>

#define BATCH 8
#define CH 256
#define CI 128
#define NPIX 3136   // 56*56
#define NCHUNK 98   // 3136/32
#define SORTN 4096
#define PADN (SORTN - NPIX) // 960
#define BN_EPS 1e-5f

// ---------------------------------------------------------------------------
// K1: fold wf_w into theta/phi weights.
// ta_w[k] = sum_c wf_w[c]*theta_w[c,k];  pb_w[k] = sum_c wf_w[CI+c]*phi_w[c,k]
// biases[0] = wf_w[:CI] . theta_b ; biases[1] = wf_w[CI:] . phi_b
// ---------------------------------------------------------------------------
__global__ __launch_bounds__(256) void k_fold(
    const float* __restrict__ wf_w,
    const float* __restrict__ theta_w, const float* __restrict__ theta_b,
    const float* __restrict__ phi_w,   const float* __restrict__ phi_b,
    float* __restrict__ ta_w, float* __restrict__ pb_w, float* __restrict__ biases)
{
    int k = threadIdx.x;  // 0..255
    float ta = 0.f, pb = 0.f;
    for (int c = 0; c < CI; ++c) {
        ta += wf_w[c]      * theta_w[c * CH + k];
        pb += wf_w[CI + c] * phi_w[c * CH + k];
    }
    ta_w[k] = ta;
    pb_w[k] = pb;
    if (k == 0) {
        float tb = 0.f, pbb = 0.f;
        for (int c = 0; c < CI; ++c) {
            tb  += wf_w[c]      * theta_b[c];
            pbb += wf_w[CI + c] * phi_b[c];
        }
        biases[0] = tb;
        biases[1] = pbb;
    }
}

// ---------------------------------------------------------------------------
// K2: g_x[b,n,o] = sum_c g_w[o,c]*x[b,c,n] + g_b[o]   (stored n-major, o inner)
//     a[b,n]    = sum_c ta_w[c]*x[b,c,n] + biases[0]
//     bsc[b,n]  = sum_c pb_w[c]*x[b,c,n] + biases[1]
// grid (98, B), block 256. LDS-staged x tile (256 x 32).
// ---------------------------------------------------------------------------
__global__ __launch_bounds__(256) void k_gx(
    const float* __restrict__ x,
    const float* __restrict__ g_w, const float* __restrict__ g_b,
    const float* __restrict__ ta_w, const float* __restrict__ pb_w,
    const float* __restrict__ biases,
    float* __restrict__ g_x, float* __restrict__ a_out, float* __restrict__ bsc_out)
{
    __shared__ float xs[CH][32];
    const int b  = blockIdx.y;
    const int n0 = blockIdx.x * 32;
    const int tid = threadIdx.x;

    // load x tile, vectorized: 256 rows x 8 float4
    for (int t = tid; t < CH * 8; t += 256) {
        int c = t >> 3, n4 = t & 7;
        const float4* src = (const float4*)(x + ((size_t)b * CH + c) * NPIX + n0);
        ((float4*)&xs[c][0])[n4] = src[n4];
    }
    __syncthreads();

    const int o  = tid & 127;
    const int nb = (tid >> 7) * 16;

    float acc[16];
#pragma unroll
    for (int i = 0; i < 16; ++i) acc[i] = 0.f;

    const float4* gw4 = (const float4*)(g_w + (size_t)o * CH);
    for (int c4 = 0; c4 < CH / 4; ++c4) {
        float4 w = gw4[c4];
        int c = c4 * 4;
#pragma unroll
        for (int i = 0; i < 16; ++i) {
            acc[i] += w.x * xs[c][nb + i] + w.y * xs[c + 1][nb + i]
                    + w.z * xs[c + 2][nb + i] + w.w * xs[c + 3][nb + i];
        }
    }
    const float gb = g_b[o];
#pragma unroll
    for (int i = 0; i < 16; ++i) {
        g_x[((size_t)b * NPIX + n0 + nb + i) * CI + o] = acc[i] + gb;
    }

    // a / bsc : threads 0..31, one pixel each
    if (tid < 32) {
        int n = tid;
        float aa = 0.f, pp = 0.f;
        for (int c = 0; c < CH; ++c) {
            float v = xs[c][n];
            aa += ta_w[c] * v;
            pp += pb_w[c] * v;
        }
        a_out[b * NPIX + n0 + n]   = aa + biases[0];
        bsc_out[b * NPIX + n0 + n] = pp + biases[1];
    }
}

// ---------------------------------------------------------------------------
// K3: per-batch bitonic sort (ascending) of bsc with original indices.
// Pad to 4096 with -FLT_MAX (pads land at front after ascending sort).
// Writes compacted s_sorted / idx_sorted (length NPIX per batch).
// grid (B), block 1024. LDS 32 KB.
// ---------------------------------------------------------------------------
__global__ __launch_bounds__(1024) void k_sort(
    const float* __restrict__ bsc,
    float* __restrict__ s_sorted, int* __restrict__ idx_sorted)
{
    __shared__ float vals[SORTN];
    __shared__ int   ids[SORTN];
    const int b = blockIdx.x;
    const int tid = threadIdx.x;

    for (int r = tid; r < SORTN; r += 1024) {
        if (r < NPIX) { vals[r] = bsc[b * NPIX + r]; ids[r] = r; }
        else          { vals[r] = -FLT_MAX;          ids[r] = -1; }
    }
    __syncthreads();

    for (int k = 2; k <= SORTN; k <<= 1) {
        for (int j = k >> 1; j > 0; j >>= 1) {
            for (int i = tid; i < SORTN; i += 1024) {
                int ixj = i ^ j;
                if (ixj > i) {
                    bool up = ((i & k) == 0);
                    float vi = vals[i], vj = vals[ixj];
                    if ((vi > vj) == up) {
                        vals[i] = vj; vals[ixj] = vi;
                        int t = ids[i]; ids[i] = ids[ixj]; ids[ixj] = t;
                    }
                }
            }
            __syncthreads();
        }
    }

    for (int r = tid; r < NPIX; r += 1024) {
        s_sorted[b * NPIX + r]   = vals[PADN + r];
        idx_sorted[b * NPIX + r] = ids[PADN + r];
    }
}

// ---------------------------------------------------------------------------
// K4a: per-chunk (32 sorted rows) partial sums of g_x and s*g_x.
// grid (NCHUNK, B), block 128 (one thread per o).
// ---------------------------------------------------------------------------
__global__ __launch_bounds__(128) void k_chunksum(
    const float* __restrict__ g_x,
    const float* __restrict__ s_sorted, const int* __restrict__ idx_sorted,
    float* __restrict__ CS1, float* __restrict__ CS2)
{
    const int b = blockIdx.y, c = blockIdx.x, o = threadIdx.x;
    float a1 = 0.f, a2 = 0.f;
    const int base = b * NPIX + c * 32;
    for (int rr = 0; rr < 32; ++rr) {
        int j = idx_sorted[base + rr];
        float v = g_x[((size_t)b * NPIX + j) * CI + o];
        a1 += v;
        a2 += s_sorted[base + rr] * v;
    }
    CS1[(b * 100 + c) * CI + o] = a1;
    CS2[(b * 100 + c) * CI + o] = a2;
}

// ---------------------------------------------------------------------------
// K4b: in-place suffix scan over the 98 chunks: CS[c] = sum_{c'>=c} raw[c'].
// Entries 98 and 99 set to 0 (used when r lands at/after the end).
// grid (B), block 128.
// ---------------------------------------------------------------------------
__global__ __launch_bounds__(128) void k_suffix(
    float* __restrict__ CS1, float* __restrict__ CS2)
{
    const int b = blockIdx.x, o = threadIdx.x;
    CS1[(b * 100 + 98) * CI + o] = 0.f;
    CS2[(b * 100 + 98) * CI + o] = 0.f;
    CS1[(b * 100 + 99) * CI + o] = 0.f;
    CS2[(b * 100 + 99) * CI + o] = 0.f;
    float a1 = 0.f, a2 = 0.f;
#pragma unroll 7
    for (int c = 97; c >= 0; --c) {
        a1 += CS1[(b * 100 + c) * CI + o];
        a2 += CS2[(b * 100 + c) * CI + o];
        CS1[(b * 100 + c) * CI + o] = a1;
        CS2[(b * 100 + c) * CI + o] = a2;
    }
}

// ---------------------------------------------------------------------------
// K5 (fused): per 32-pixel tile:
//   A) binary search rank r_n for each pixel (threads 0..31)
//   B) y[n,o] = (t_n * S1 + S2)/N, S = coarse suffix + <=31-row remainder
//   C) z[c,n] = BN(wz_w @ y^T + wz_b) + x  -> out
// grid (98, B), block 256.
// ---------------------------------------------------------------------------
__global__ __launch_bounds__(256) void k_final(
    const float* __restrict__ x, const float* __restrict__ g_x,
    const float* __restrict__ a_arr, const float* __restrict__ wf_b,
    const float* __restrict__ s_sorted, const int* __restrict__ idx_sorted,
    const float* __restrict__ CS1, const float* __restrict__ CS2,
    const float* __restrict__ wz_w, const float* __restrict__ wz_b,
    const float* __restrict__ bn_g, const float* __restrict__ bn_b,
    const float* __restrict__ bn_m, const float* __restrict__ bn_v,
    float* __restrict__ out)
{
    __shared__ float ys[32][CI];
    __shared__ int   rs[32];
    __shared__ float ts[32];

    const int b = blockIdx.y;
    const int n0 = blockIdx.x * 32;
    const int tid = threadIdx.x;

    if (tid < 32) {
        float t = a_arr[b * NPIX + n0 + tid] + wf_b[0];
        float key = -t;
        const float* s = s_sorted + b * NPIX;
        int lo = 0, hi = NPIX;
        while (lo < hi) {
            int mid = (lo + hi) >> 1;
            if (s[mid] > key) hi = mid; else lo = mid + 1;
        }
        rs[tid] = lo;
        ts[tid] = t;
    }
    __syncthreads();

    const int o = tid & 127;
    const int h = tid >> 7;
    const float invN = 1.0f / (float)NPIX;

    for (int n = h * 16; n < h * 16 + 16; ++n) {
        int r = rs[n];
        float t = ts[n];
        int c = r >> 5;                      // chunk index, may be 98 when r==NPIX
        int end = (c + 1) * 32;
        if (end > NPIX) end = NPIX;
        float r1 = 0.f, r2 = 0.f;
        for (int rr = r; rr < end; ++rr) {
            int j = idx_sorted[b * NPIX + rr];
            float v = g_x[((size_t)b * NPIX + j) * CI + o];
            r1 += v;
            r2 += s_sorted[b * NPIX + rr] * v;
        }
        int cbase = (b * 100 + c + 1) * CI + o;   // c+1 in [1,99]; 98/99 are zero
        float S1 = CS1[cbase] + r1;
        float S2 = CS2[cbase] + r2;
        ys[n][o] = (t * S1 + S2) * invN;
    }
    __syncthreads();

    // stage C: one thread per output channel
    const int cc = tid;  // 0..255
    float acc[32];
#pragma unroll
    for (int n = 0; n < 32; ++n) acc[n] = 0.f;

    const float4* wz4 = (const float4*)(wz_w + (size_t)cc * CI);
    for (int o4 = 0; o4 < CI / 4; ++o4) {
        float4 w = wz4[o4];
#pragma unroll
        for (int n = 0; n < 32; ++n) {
            float4 yv = *((const float4*)&ys[n][o4 * 4]);
            acc[n] += w.x * yv.x + w.y * yv.y + w.z * yv.z + w.w * yv.w;
        }
    }

    const float inv  = bn_g[cc] * rsqrtf(bn_v[cc] + BN_EPS);
    const float bias = (wz_b[cc] - bn_m[cc]) * inv + bn_b[cc];

    const float4* xp = (const float4*)(x   + ((size_t)b * CH + cc) * NPIX + n0);
    float4*       op = (float4*)      (out + ((size_t)b * CH + cc) * NPIX + n0);
#pragma unroll
    for (int n4 = 0; n4 < 8; ++n4) {
        float4 xv = xp[n4];
        float4 ov;
        ov.x = acc[n4 * 4 + 0] * inv + bias + xv.x;
        ov.y = acc[n4 * 4 + 1] * inv + bias + xv.y;
        ov.z = acc[n4 * 4 + 2] * inv + bias + xv.z;
        ov.w = acc[n4 * 4 + 3] * inv + bias + xv.w;
        op[n4] = ov;
    }
}

// ---------------------------------------------------------------------------
extern "C" void kernel_launch(void* const* d_in, const int* in_sizes, int n_in,
                              void* d_out, int out_size, void* d_ws, size_t ws_size,
                              hipStream_t stream)
{
    const float* x       = (const float*)d_in[0];
    const float* g_w     = (const float*)d_in[1];
    const float* g_b     = (const float*)d_in[2];
    const float* theta_w = (const float*)d_in[3];
    const float* theta_b = (const float*)d_in[4];
    const float* phi_w   = (const float*)d_in[5];
    const float* phi_b   = (const float*)d_in[6];
    const float* wf_w    = (const float*)d_in[7];
    const float* wf_b    = (const float*)d_in[8];
    const float* wz_w    = (const float*)d_in[9];
    const float* wz_b    = (const float*)d_in[10];
    const float* bn_g    = (const float*)d_in[11];
    const float* bn_b    = (const float*)d_in[12];
    const float* bn_m    = (const float*)d_in[13];
    const float* bn_v    = (const float*)d_in[14];

    float* ws = (float*)d_ws;
    float* ta_w   = ws;                       // 256
    float* pb_w   = ws + 256;                 // 256
    float* biases = ws + 512;                 // 2 (pad to 4)
    float* g_x    = ws + 516;                 // B*NPIX*CI
    float* a_arr  = g_x + (size_t)BATCH * NPIX * CI;   // B*NPIX
    float* bsc    = a_arr + BATCH * NPIX;              // B*NPIX
    float* s_sorted = bsc + BATCH * NPIX;              // B*NPIX
    int*   idx_sorted = (int*)(s_sorted + BATCH * NPIX); // B*NPIX ints
    float* CS1    = (float*)(idx_sorted + BATCH * NPIX); // B*100*CI
    float* CS2    = CS1 + BATCH * 100 * CI;              // B*100*CI

    k_fold<<<1, 256, 0, stream>>>(wf_w, theta_w, theta_b, phi_w, phi_b,
                                  ta_w, pb_w, biases);

    k_gx<<<dim3(NCHUNK, BATCH), 256, 0, stream>>>(
        x, g_w, g_b, ta_w, pb_w, biases, g_x, a_arr, bsc);

    k_sort<<<BATCH, 1024, 0, stream>>>(bsc, s_sorted, idx_sorted);

    k_chunksum<<<dim3(NCHUNK, BATCH), 128, 0, stream>>>(
        g_x, s_sorted, idx_sorted, CS1, CS2);

    k_suffix<<<BATCH, 128, 0, stream>>>(CS1, CS2);

    k_final<<<dim3(NCHUNK, BATCH), 256, 0, stream>>>(
        x, g_x, a_arr, wf_b, s_sorted, idx_sorted, CS1, CS2,
        wz_w, wz_b, bn_g, bn_b, bn_m, bn_v, (float*)d_out);
}

// Round 2
// 310.177 us; speedup vs baseline: 1.4622x; 1.4622x over previous
//
#include <hip/hip_runtime.h>
#include <cfloat>
#include <math.h>

#define BATCH 8
#define CH 256
#define CI 128
#define NPIX 3136   // 56*56
#define NCHUNK 98   // 3136/32
#define SORTN 4096
#define PADN (SORTN - NPIX) // 960
#define NR (NPIX + 1)       // suffix rows incl. rank==NPIX (zero row)
#define BN_EPS 1e-5f

// ---------------------------------------------------------------------------
// K1: fold wf_w into theta/phi weights.
// ---------------------------------------------------------------------------
__global__ __launch_bounds__(256) void k_fold(
    const float* __restrict__ wf_w,
    const float* __restrict__ theta_w, const float* __restrict__ theta_b,
    const float* __restrict__ phi_w,   const float* __restrict__ phi_b,
    float* __restrict__ ta_w, float* __restrict__ pb_w, float* __restrict__ biases)
{
    int k = threadIdx.x;  // 0..255
    float ta = 0.f, pb = 0.f;
    for (int c = 0; c < CI; ++c) {
        ta += wf_w[c]      * theta_w[c * CH + k];
        pb += wf_w[CI + c] * phi_w[c * CH + k];
    }
    ta_w[k] = ta;
    pb_w[k] = pb;
    if (k == 0) {
        float tb = 0.f, pbb = 0.f;
        for (int c = 0; c < CI; ++c) {
            tb  += wf_w[c]      * theta_b[c];
            pbb += wf_w[CI + c] * phi_b[c];
        }
        biases[0] = tb;
        biases[1] = pbb;
    }
}

// ---------------------------------------------------------------------------
// K2: g_x[b,n,o] (n-major, o inner) + a[b,n] + bsc[b,n]
// grid (98, B), block 256. LDS-staged x tile (256 x 32).
// ---------------------------------------------------------------------------
__global__ __launch_bounds__(256) void k_gx(
    const float* __restrict__ x,
    const float* __restrict__ g_w, const float* __restrict__ g_b,
    const float* __restrict__ ta_w, const float* __restrict__ pb_w,
    const float* __restrict__ biases,
    float* __restrict__ g_x, float* __restrict__ a_out, float* __restrict__ bsc_out)
{
    __shared__ float xs[CH][32];
    const int b  = blockIdx.y;
    const int n0 = blockIdx.x * 32;
    const int tid = threadIdx.x;

    for (int t = tid; t < CH * 8; t += 256) {
        int c = t >> 3, n4 = t & 7;
        const float4* src = (const float4*)(x + ((size_t)b * CH + c) * NPIX + n0);
        ((float4*)&xs[c][0])[n4] = src[n4];
    }
    __syncthreads();

    const int o  = tid & 127;
    const int nb = (tid >> 7) * 16;

    float acc[16];
#pragma unroll
    for (int i = 0; i < 16; ++i) acc[i] = 0.f;

    const float4* gw4 = (const float4*)(g_w + (size_t)o * CH);
    for (int c4 = 0; c4 < CH / 4; ++c4) {
        float4 w = gw4[c4];
        int c = c4 * 4;
#pragma unroll
        for (int i = 0; i < 16; ++i) {
            acc[i] += w.x * xs[c][nb + i] + w.y * xs[c + 1][nb + i]
                    + w.z * xs[c + 2][nb + i] + w.w * xs[c + 3][nb + i];
        }
    }
    const float gb = g_b[o];
#pragma unroll
    for (int i = 0; i < 16; ++i) {
        g_x[((size_t)b * NPIX + n0 + nb + i) * CI + o] = acc[i] + gb;
    }

    if (tid < 32) {
        int n = tid;
        float aa = 0.f, pp = 0.f;
        for (int c = 0; c < CH; ++c) {
            float v = xs[c][n];
            aa += ta_w[c] * v;
            pp += pb_w[c] * v;
        }
        a_out[b * NPIX + n0 + n]   = aa + biases[0];
        bsc_out[b * NPIX + n0 + n] = pp + biases[1];
    }
}

// ---------------------------------------------------------------------------
// K3: per-batch bitonic sort (ascending) of bsc with original indices.
// ---------------------------------------------------------------------------
__global__ __launch_bounds__(1024) void k_sort(
    const float* __restrict__ bsc,
    float* __restrict__ s_sorted, int* __restrict__ idx_sorted)
{
    __shared__ float vals[SORTN];
    __shared__ int   ids[SORTN];
    const int b = blockIdx.x;
    const int tid = threadIdx.x;

    for (int r = tid; r < SORTN; r += 1024) {
        if (r < NPIX) { vals[r] = bsc[b * NPIX + r]; ids[r] = r; }
        else          { vals[r] = -FLT_MAX;          ids[r] = -1; }
    }
    __syncthreads();

    for (int k = 2; k <= SORTN; k <<= 1) {
        for (int j = k >> 1; j > 0; j >>= 1) {
            for (int i = tid; i < SORTN; i += 1024) {
                int ixj = i ^ j;
                if (ixj > i) {
                    bool up = ((i & k) == 0);
                    float vi = vals[i], vj = vals[ixj];
                    if ((vi > vj) == up) {
                        vals[i] = vj; vals[ixj] = vi;
                        int t = ids[i]; ids[i] = ids[ixj]; ids[ixj] = t;
                    }
                }
            }
            __syncthreads();
        }
    }

    for (int r = tid; r < NPIX; r += 1024) {
        s_sorted[b * NPIX + r]   = vals[PADN + r];
        idx_sorted[b * NPIX + r] = ids[PADN + r];
    }
}

// ---------------------------------------------------------------------------
// K4a: per-chunk (32 sorted rows) partial sums of g_x and s*g_x.
// grid (NCHUNK, B), block 128.
// ---------------------------------------------------------------------------
__global__ __launch_bounds__(128) void k_chunksum(
    const float* __restrict__ g_x,
    const float* __restrict__ s_sorted, const int* __restrict__ idx_sorted,
    float* __restrict__ CS1, float* __restrict__ CS2)
{
    const int b = blockIdx.y, c = blockIdx.x, o = threadIdx.x;
    float a1 = 0.f, a2 = 0.f;
    const int base = b * NPIX + c * 32;
#pragma unroll 8
    for (int rr = 0; rr < 32; ++rr) {
        int j = idx_sorted[base + rr];
        float v = g_x[((size_t)b * NPIX + j) * CI + o];
        a1 += v;
        a2 += s_sorted[base + rr] * v;
    }
    CS1[(b * 100 + c) * CI + o] = a1;
    CS2[(b * 100 + c) * CI + o] = a2;
}

// ---------------------------------------------------------------------------
// K4b: in-place suffix scan over the 98 chunks; also zero S1/S2 row NPIX.
// grid (B), block 128.
// ---------------------------------------------------------------------------
__global__ __launch_bounds__(128) void k_suffix(
    float* __restrict__ CS1, float* __restrict__ CS2,
    float* __restrict__ S1,  float* __restrict__ S2)
{
    const int b = blockIdx.x, o = threadIdx.x;
    CS1[(b * 100 + 98) * CI + o] = 0.f;
    CS2[(b * 100 + 98) * CI + o] = 0.f;
    CS1[(b * 100 + 99) * CI + o] = 0.f;
    CS2[(b * 100 + 99) * CI + o] = 0.f;
    S1[((size_t)b * NR + NPIX) * CI + o] = 0.f;
    S2[((size_t)b * NR + NPIX) * CI + o] = 0.f;
    float a1 = 0.f, a2 = 0.f;
#pragma unroll 7
    for (int c = 97; c >= 0; --c) {
        a1 += CS1[(b * 100 + c) * CI + o];
        a2 += CS2[(b * 100 + c) * CI + o];
        CS1[(b * 100 + c) * CI + o] = a1;
        CS2[(b * 100 + c) * CI + o] = a2;
    }
}

// ---------------------------------------------------------------------------
// K4c: expand to full per-rank suffix arrays.
// S1[b,r,o] = CS1[chunk(r)+1] + within-chunk suffix.  grid (NCHUNK, B), blk 128.
// ---------------------------------------------------------------------------
__global__ __launch_bounds__(128) void k_expand(
    const float* __restrict__ g_x,
    const float* __restrict__ s_sorted, const int* __restrict__ idx_sorted,
    const float* __restrict__ CS1, const float* __restrict__ CS2,
    float* __restrict__ S1, float* __restrict__ S2)
{
    const int b = blockIdx.y, c = blockIdx.x, o = threadIdx.x;
    float a1 = CS1[(b * 100 + c + 1) * CI + o];
    float a2 = CS2[(b * 100 + c + 1) * CI + o];
    const int base = b * NPIX + c * 32;
#pragma unroll 8
    for (int rr = 31; rr >= 0; --rr) {
        int j = idx_sorted[base + rr];
        float v = g_x[((size_t)b * NPIX + j) * CI + o];
        a1 += v;
        a2 += s_sorted[base + rr] * v;
        S1[((size_t)b * NR + c * 32 + rr) * CI + o] = a1;
        S2[((size_t)b * NR + c * 32 + rr) * CI + o] = a2;
    }
}

// ---------------------------------------------------------------------------
// K5 (fused): binary search -> y row via 2 suffix-row loads -> wz GEMM ->
// BN -> residual -> out.  grid (98, B), block 256.
// ---------------------------------------------------------------------------
__global__ __launch_bounds__(256) void k_final(
    const float* __restrict__ x,
    const float* __restrict__ a_arr, const float* __restrict__ wf_b,
    const float* __restrict__ s_sorted,
    const float* __restrict__ S1, const float* __restrict__ S2,
    const float* __restrict__ wz_w, const float* __restrict__ wz_b,
    const float* __restrict__ bn_g, const float* __restrict__ bn_b,
    const float* __restrict__ bn_m, const float* __restrict__ bn_v,
    float* __restrict__ out)
{
    __shared__ float ys[32][CI];
    __shared__ int   rs[32];
    __shared__ float ts[32];

    const int b = blockIdx.y;
    const int n0 = blockIdx.x * 32;
    const int tid = threadIdx.x;

    if (tid < 32) {
        float t = a_arr[b * NPIX + n0 + tid] + wf_b[0];
        float key = -t;
        const float* s = s_sorted + b * NPIX;
        int lo = 0, hi = NPIX;
        while (lo < hi) {
            int mid = (lo + hi) >> 1;
            if (s[mid] > key) hi = mid; else lo = mid + 1;
        }
        rs[tid] = lo;
        ts[tid] = t;
    }
    __syncthreads();

    const int o = tid & 127;
    const int h = tid >> 7;
    const float invN = 1.0f / (float)NPIX;

#pragma unroll 4
    for (int n = h * 16; n < h * 16 + 16; ++n) {
        int r = rs[n];
        float t = ts[n];
        size_t rowoff = ((size_t)b * NR + r) * CI + o;
        ys[n][o] = (t * S1[rowoff] + S2[rowoff]) * invN;
    }
    __syncthreads();

    // wz GEMM + BN + residual: one thread per output channel
    const int cc = tid;  // 0..255
    float acc[32];
#pragma unroll
    for (int n = 0; n < 32; ++n) acc[n] = 0.f;

    const float4* wz4 = (const float4*)(wz_w + (size_t)cc * CI);
    for (int o4 = 0; o4 < CI / 4; ++o4) {
        float4 w = wz4[o4];
#pragma unroll
        for (int n = 0; n < 32; ++n) {
            float4 yv = *((const float4*)&ys[n][o4 * 4]);
            acc[n] += w.x * yv.x + w.y * yv.y + w.z * yv.z + w.w * yv.w;
        }
    }

    const float inv  = bn_g[cc] * rsqrtf(bn_v[cc] + BN_EPS);
    const float bias = (wz_b[cc] - bn_m[cc]) * inv + bn_b[cc];

    const float4* xp = (const float4*)(x   + ((size_t)b * CH + cc) * NPIX + n0);
    float4*       op = (float4*)      (out + ((size_t)b * CH + cc) * NPIX + n0);
#pragma unroll
    for (int n4 = 0; n4 < 8; ++n4) {
        float4 xv = xp[n4];
        float4 ov;
        ov.x = acc[n4 * 4 + 0] * inv + bias + xv.x;
        ov.y = acc[n4 * 4 + 1] * inv + bias + xv.y;
        ov.z = acc[n4 * 4 + 2] * inv + bias + xv.z;
        ov.w = acc[n4 * 4 + 3] * inv + bias + xv.w;
        op[n4] = ov;
    }
}

// ---------------------------------------------------------------------------
extern "C" void kernel_launch(void* const* d_in, const int* in_sizes, int n_in,
                              void* d_out, int out_size, void* d_ws, size_t ws_size,
                              hipStream_t stream)
{
    const float* x       = (const float*)d_in[0];
    const float* g_w     = (const float*)d_in[1];
    const float* g_b     = (const float*)d_in[2];
    const float* theta_w = (const float*)d_in[3];
    const float* theta_b = (const float*)d_in[4];
    const float* phi_w   = (const float*)d_in[5];
    const float* phi_b   = (const float*)d_in[6];
    const float* wf_w    = (const float*)d_in[7];
    const float* wf_b    = (const float*)d_in[8];
    const float* wz_w    = (const float*)d_in[9];
    const float* wz_b    = (const float*)d_in[10];
    const float* bn_g    = (const float*)d_in[11];
    const float* bn_b    = (const float*)d_in[12];
    const float* bn_m    = (const float*)d_in[13];
    const float* bn_v    = (const float*)d_in[14];

    float* ws = (float*)d_ws;
    float* ta_w   = ws;                       // 256
    float* pb_w   = ws + 256;                 // 256
    float* biases = ws + 512;                 // 4
    float* g_x    = ws + 516;                                  // B*NPIX*CI
    float* a_arr  = g_x + (size_t)BATCH * NPIX * CI;           // B*NPIX
    float* bsc    = a_arr + BATCH * NPIX;                      // B*NPIX
    float* s_sorted = bsc + BATCH * NPIX;                      // B*NPIX
    int*   idx_sorted = (int*)(s_sorted + BATCH * NPIX);       // B*NPIX ints
    float* CS1    = (float*)(idx_sorted + BATCH * NPIX);       // B*100*CI
    float* CS2    = CS1 + BATCH * 100 * CI;                    // B*100*CI
    float* S1     = CS2 + BATCH * 100 * CI;                    // B*NR*CI
    float* S2     = S1 + (size_t)BATCH * NR * CI;              // B*NR*CI

    k_fold<<<1, 256, 0, stream>>>(wf_w, theta_w, theta_b, phi_w, phi_b,
                                  ta_w, pb_w, biases);

    k_gx<<<dim3(NCHUNK, BATCH), 256, 0, stream>>>(
        x, g_w, g_b, ta_w, pb_w, biases, g_x, a_arr, bsc);

    k_sort<<<BATCH, 1024, 0, stream>>>(bsc, s_sorted, idx_sorted);

    k_chunksum<<<dim3(NCHUNK, BATCH), 128, 0, stream>>>(
        g_x, s_sorted, idx_sorted, CS1, CS2);

    k_suffix<<<BATCH, 128, 0, stream>>>(CS1, CS2, S1, S2);

    k_expand<<<dim3(NCHUNK, BATCH), 128, 0, stream>>>(
        g_x, s_sorted, idx_sorted, CS1, CS2, S1, S2);

    k_final<<<dim3(NCHUNK, BATCH), 256, 0, stream>>>(
        x, a_arr, wf_b, s_sorted, S1, S2,
        wz_w, wz_b, bn_g, bn_b, bn_m, bn_v, (float*)d_out);
}

// Round 3
// 265.697 us; speedup vs baseline: 1.7069x; 1.1674x over previous
//
#include <hip/hip_runtime.h>
#include <cfloat>
#include <math.h>

#define BATCH 8
#define CH 256
#define CI 128
#define NPIX 3136   // 56*56
#define NCHUNK 98   // 3136/32
#define NR (NPIX + 1)       // suffix rows incl. rank==NPIX (zero row)
#define NB 4096             // buckets for the scatter sort
#define BN_EPS 1e-5f

__device__ __forceinline__ float bf2f(unsigned short u) {
    union { unsigned int i; float f; } x; x.i = ((unsigned int)u) << 16; return x.f;
}
__device__ __forceinline__ unsigned short f2bf(float f) {
    union { float f; unsigned int i; } x; x.f = f;
    unsigned int u = x.i;
    return (unsigned short)((u + 0x7FFFu + ((u >> 16) & 1u)) >> 16);  // RNE
}

// ---------------------------------------------------------------------------
// K1: fold wf_w into theta/phi weights.
// ---------------------------------------------------------------------------
__global__ __launch_bounds__(256) void k_fold(
    const float* __restrict__ wf_w,
    const float* __restrict__ theta_w, const float* __restrict__ theta_b,
    const float* __restrict__ phi_w,   const float* __restrict__ phi_b,
    float* __restrict__ ta_w, float* __restrict__ pb_w, float* __restrict__ biases)
{
    int k = threadIdx.x;  // 0..255
    float ta = 0.f, pb = 0.f;
    for (int c = 0; c < CI; ++c) {
        ta += wf_w[c]      * theta_w[c * CH + k];
        pb += wf_w[CI + c] * phi_w[c * CH + k];
    }
    ta_w[k] = ta;
    pb_w[k] = pb;
    if (k == 0) {
        float tb = 0.f, pbb = 0.f;
        for (int c = 0; c < CI; ++c) {
            tb  += wf_w[c]      * theta_b[c];
            pbb += wf_w[CI + c] * phi_b[c];
        }
        biases[0] = tb;
        biases[1] = pbb;
    }
}

// ---------------------------------------------------------------------------
// K2: g_x[b,n,o] (n-major, o inner, bf16) + a[b,n] + bsc[b,n] (fp32)
// grid (98, B), block 256. LDS-staged x tile (256 x 32).
// ---------------------------------------------------------------------------
__global__ __launch_bounds__(256) void k_gx(
    const float* __restrict__ x,
    const float* __restrict__ g_w, const float* __restrict__ g_b,
    const float* __restrict__ ta_w, const float* __restrict__ pb_w,
    const float* __restrict__ biases,
    unsigned short* __restrict__ gx16,
    float* __restrict__ a_out, float* __restrict__ bsc_out)
{
    __shared__ float xs[CH][32];
    const int b  = blockIdx.y;
    const int n0 = blockIdx.x * 32;
    const int tid = threadIdx.x;

    for (int t = tid; t < CH * 8; t += 256) {
        int c = t >> 3, n4 = t & 7;
        const float4* src = (const float4*)(x + ((size_t)b * CH + c) * NPIX + n0);
        ((float4*)&xs[c][0])[n4] = src[n4];
    }
    __syncthreads();

    const int o  = tid & 127;
    const int nb = (tid >> 7) * 16;

    float acc[16];
#pragma unroll
    for (int i = 0; i < 16; ++i) acc[i] = 0.f;

    const float4* gw4 = (const float4*)(g_w + (size_t)o * CH);
    for (int c4 = 0; c4 < CH / 4; ++c4) {
        float4 w = gw4[c4];
        int c = c4 * 4;
#pragma unroll
        for (int i = 0; i < 16; ++i) {
            acc[i] += w.x * xs[c][nb + i] + w.y * xs[c + 1][nb + i]
                    + w.z * xs[c + 2][nb + i] + w.w * xs[c + 3][nb + i];
        }
    }
    const float gb = g_b[o];
#pragma unroll
    for (int i = 0; i < 16; ++i) {
        gx16[((size_t)b * NPIX + n0 + nb + i) * CI + o] = f2bf(acc[i] + gb);
    }

    if (tid < 32) {
        int n = tid;
        float aa = 0.f, pp = 0.f;
        for (int c = 0; c < CH; ++c) {
            float v = xs[c][n];
            aa += ta_w[c] * v;
            pp += pb_w[c] * v;
        }
        a_out[b * NPIX + n0 + n]   = aa + biases[0];
        bsc_out[b * NPIX + n0 + n] = pp + biases[1];
    }
}

// ---------------------------------------------------------------------------
// K3: per-batch bucket scatter "sort": min/max -> 4096-bucket histogram ->
// block scan -> atomic scatter. Output: values/indices grouped by ascending
// bucket, bucket start table, and (bmin, scale) params for queries.
// grid (B), block 1024.
// ---------------------------------------------------------------------------
__global__ __launch_bounds__(1024) void k_bucketsort(
    const float* __restrict__ bsc,
    float* __restrict__ s_sorted, int* __restrict__ idx_sorted,
    int* __restrict__ bstart, float* __restrict__ params)
{
    __shared__ float vals[NPIX];            // 12.25 KB
    __shared__ unsigned short qarr[NPIX];   // 6.1 KB
    __shared__ int hist[NB];                // 16 KB (reused as start table)
    __shared__ int cnt[NB];                 // 16 KB
    __shared__ float red[1024];             // 4 KB (reused as psum)
    __shared__ float red2[1024];            // 4 KB
    __shared__ float sh_min, sh_scale;

    const int b = blockIdx.x, tid = threadIdx.x;

    float lmin = FLT_MAX, lmax = -FLT_MAX;
    for (int i = tid; i < NPIX; i += 1024) {
        float v = bsc[b * NPIX + i];
        vals[i] = v;
        lmin = fminf(lmin, v);
        lmax = fmaxf(lmax, v);
    }
    red[tid] = lmin; red2[tid] = lmax;
    __syncthreads();
    for (int off = 512; off > 0; off >>= 1) {
        if (tid < off) {
            red[tid]  = fminf(red[tid],  red[tid + off]);
            red2[tid] = fmaxf(red2[tid], red2[tid + off]);
        }
        __syncthreads();
    }
    if (tid == 0) {
        float mn = red[0], mx = red2[0];
        float range = mx - mn;
        float scale = (range > 0.f) ? (float)NB / range : 0.f;
        sh_min = mn; sh_scale = scale;
        params[b * 2] = mn; params[b * 2 + 1] = scale;
    }
    for (int i = tid; i < NB; i += 1024) { hist[i] = 0; cnt[i] = 0; }
    __syncthreads();

    const float bmin = sh_min, scale = sh_scale;
    for (int i = tid; i < NPIX; i += 1024) {
        int q = (int)((vals[i] - bmin) * scale);
        q = (q < 0) ? 0 : ((q > NB - 1) ? NB - 1 : q);
        qarr[i] = (unsigned short)q;
        atomicAdd(&hist[q], 1);
    }
    __syncthreads();

    // block exclusive scan of hist (4 buckets per thread)
    int* psum = (int*)red;
    const int base4 = tid * 4;
    int h0 = hist[base4], h1 = hist[base4 + 1], h2 = hist[base4 + 2], h3 = hist[base4 + 3];
    psum[tid] = h0 + h1 + h2 + h3;
    __syncthreads();
    for (int off = 1; off < 1024; off <<= 1) {
        int v = psum[tid];
        int w = (tid >= off) ? psum[tid - off] : 0;
        __syncthreads();
        psum[tid] = v + w;
        __syncthreads();
    }
    int excl = (tid == 0) ? 0 : psum[tid - 1];
    hist[base4]     = excl;
    hist[base4 + 1] = excl + h0;
    hist[base4 + 2] = excl + h0 + h1;
    hist[base4 + 3] = excl + h0 + h1 + h2;
    __syncthreads();

    for (int i = tid; i < NB; i += 1024) bstart[b * (NB + 1) + i] = hist[i];
    if (tid == 0) bstart[b * (NB + 1) + NB] = NPIX;

    // scatter (within-bucket order arbitrary; only permutes sum order)
    for (int i = tid; i < NPIX; i += 1024) {
        int q = qarr[i];
        int pos = hist[q] + atomicAdd(&cnt[q], 1);
        s_sorted[b * NPIX + pos]   = vals[i];
        idx_sorted[b * NPIX + pos] = i;
    }
}

// ---------------------------------------------------------------------------
// K4a: per-chunk (32 scattered rows) partial sums of g_x and s*g_x (fp32 acc).
// grid (NCHUNK, B), block 128.
// ---------------------------------------------------------------------------
__global__ __launch_bounds__(128) void k_chunksum(
    const unsigned short* __restrict__ gx16,
    const float* __restrict__ s_sorted, const int* __restrict__ idx_sorted,
    float* __restrict__ CS1, float* __restrict__ CS2)
{
    const int b = blockIdx.y, c = blockIdx.x, o = threadIdx.x;
    float a1 = 0.f, a2 = 0.f;
    const int base = b * NPIX + c * 32;
#pragma unroll 8
    for (int rr = 0; rr < 32; ++rr) {
        int j = idx_sorted[base + rr];
        float v = bf2f(gx16[((size_t)(b * NPIX + j)) * CI + o]);
        a1 += v;
        a2 += s_sorted[base + rr] * v;
    }
    CS1[(b * 100 + c) * CI + o] = a1;
    CS2[(b * 100 + c) * CI + o] = a2;
}

// ---------------------------------------------------------------------------
// K4b: suffix scan over the 98 chunks, LDS-staged (bulk coalesced load,
// scan in LDS, bulk store). Also zeroes CS rows 98/99 and S12 row NPIX.
// grid (B), block 128.
// ---------------------------------------------------------------------------
__global__ __launch_bounds__(128) void k_suffix(
    float* __restrict__ CS1, float* __restrict__ CS2,
    unsigned int* __restrict__ S12)
{
    __shared__ float buf[NCHUNK * CI];   // 49 KB
    const int b = blockIdx.x, tid = threadIdx.x;

    // ---- CS1 ----
    for (int i = tid; i < NCHUNK * CI; i += 128) buf[i] = CS1[b * 100 * CI + i];
    __syncthreads();
    {
        float acc = 0.f;
        for (int c = NCHUNK - 1; c >= 0; --c) {
            acc += buf[c * CI + tid];
            buf[c * CI + tid] = acc;
        }
    }
    __syncthreads();
    for (int i = tid; i < NCHUNK * CI; i += 128) CS1[b * 100 * CI + i] = buf[i];
    CS1[(b * 100 + 98) * CI + tid] = 0.f;
    CS1[(b * 100 + 99) * CI + tid] = 0.f;
    __syncthreads();

    // ---- CS2 ----
    for (int i = tid; i < NCHUNK * CI; i += 128) buf[i] = CS2[b * 100 * CI + i];
    __syncthreads();
    {
        float acc = 0.f;
        for (int c = NCHUNK - 1; c >= 0; --c) {
            acc += buf[c * CI + tid];
            buf[c * CI + tid] = acc;
        }
    }
    __syncthreads();
    for (int i = tid; i < NCHUNK * CI; i += 128) CS2[b * 100 * CI + i] = buf[i];
    CS2[(b * 100 + 98) * CI + tid] = 0.f;
    CS2[(b * 100 + 99) * CI + tid] = 0.f;

    S12[((size_t)b * NR + NPIX) * CI + tid] = 0u;   // zero suffix row at rank NPIX
}

// ---------------------------------------------------------------------------
// K4c: expand to full per-rank suffix arrays, packed bf16 (S1 lo, S2 hi).
// grid (NCHUNK, B), block 128.
// ---------------------------------------------------------------------------
__global__ __launch_bounds__(128) void k_expand(
    const unsigned short* __restrict__ gx16,
    const float* __restrict__ s_sorted, const int* __restrict__ idx_sorted,
    const float* __restrict__ CS1, const float* __restrict__ CS2,
    unsigned int* __restrict__ S12)
{
    const int b = blockIdx.y, c = blockIdx.x, o = threadIdx.x;
    float a1 = CS1[(b * 100 + c + 1) * CI + o];
    float a2 = CS2[(b * 100 + c + 1) * CI + o];
    const int base = b * NPIX + c * 32;
#pragma unroll 8
    for (int rr = 31; rr >= 0; --rr) {
        int j = idx_sorted[base + rr];
        float v = bf2f(gx16[((size_t)(b * NPIX + j)) * CI + o]);
        a1 += v;
        a2 += s_sorted[base + rr] * v;
        unsigned int pack = (unsigned int)f2bf(a1) | ((unsigned int)f2bf(a2) << 16);
        S12[((size_t)b * NR + c * 32 + rr) * CI + o] = pack;
    }
}

// ---------------------------------------------------------------------------
// K5 (fused): bucket lookup (no binary search) -> y row via ONE packed
// suffix-row load + exact boundary-bucket remainder -> wz GEMM -> BN ->
// residual -> out.  grid (98, B), block 256.
// ---------------------------------------------------------------------------
__global__ __launch_bounds__(256) void k_final(
    const float* __restrict__ x,
    const float* __restrict__ a_arr, const float* __restrict__ wf_b,
    const float* __restrict__ s_sorted, const int* __restrict__ idx_sorted,
    const unsigned short* __restrict__ gx16,
    const unsigned int* __restrict__ S12,
    const int* __restrict__ bstart, const float* __restrict__ params,
    const float* __restrict__ wz_w, const float* __restrict__ wz_b,
    const float* __restrict__ bn_g, const float* __restrict__ bn_b,
    const float* __restrict__ bn_m, const float* __restrict__ bn_v,
    float* __restrict__ out)
{
    __shared__ float ys[32][CI];
    __shared__ int   rs[32], p0s[32], p1s[32];
    __shared__ float ts[32];

    const int b = blockIdx.y;
    const int n0 = blockIdx.x * 32;
    const int tid = threadIdx.x;

    if (tid < 32) {
        float t = a_arr[b * NPIX + n0 + tid] + wf_b[0];
        float key = -t;
        float bmin = params[b * 2], scale = params[b * 2 + 1];
        float fq = (key - bmin) * scale;
        int r0, p0, p1;
        if (fq < 0.f) {              // key below all values: everything included
            r0 = 0; p0 = 0; p1 = 0;
        } else {
            int kb = (int)fq;
            if (kb >= NB) {          // key above all values: nothing included
                r0 = NPIX; p0 = 0; p1 = 0;
            } else {                 // buckets > kb fully in; bucket kb tested exactly
                p0 = bstart[b * (NB + 1) + kb];
                p1 = bstart[b * (NB + 1) + kb + 1];
                r0 = p1;
            }
        }
        rs[tid] = r0; p0s[tid] = p0; p1s[tid] = p1; ts[tid] = t;
    }
    __syncthreads();

    const int o = tid & 127;
    const int h = tid >> 7;
    const float invN = 1.0f / (float)NPIX;

    for (int n = h * 16; n < h * 16 + 16; ++n) {
        float t = ts[n];
        unsigned int pack = S12[((size_t)b * NR + rs[n]) * CI + o];
        float S1 = bf2f((unsigned short)(pack & 0xFFFFu));
        float S2 = bf2f((unsigned short)(pack >> 16));
        // boundary bucket: loop bounds & branch are wave-uniform (bv broadcast)
        for (int rr = p0s[n]; rr < p1s[n]; ++rr) {
            float bv = s_sorted[b * NPIX + rr];
            if (bv > -t) {
                int j = idx_sorted[b * NPIX + rr];
                float v = bf2f(gx16[((size_t)(b * NPIX + j)) * CI + o]);
                S1 += v;
                S2 += bv * v;
            }
        }
        ys[n][o] = (t * S1 + S2) * invN;
    }
    __syncthreads();

    // wz GEMM + BN + residual: one thread per output channel
    const int cc = tid;  // 0..255
    float acc[32];
#pragma unroll
    for (int n = 0; n < 32; ++n) acc[n] = 0.f;

    const float4* wz4 = (const float4*)(wz_w + (size_t)cc * CI);
    for (int o4 = 0; o4 < CI / 4; ++o4) {
        float4 w = wz4[o4];
#pragma unroll
        for (int n = 0; n < 32; ++n) {
            float4 yv = *((const float4*)&ys[n][o4 * 4]);
            acc[n] += w.x * yv.x + w.y * yv.y + w.z * yv.z + w.w * yv.w;
        }
    }

    const float inv  = bn_g[cc] * rsqrtf(bn_v[cc] + BN_EPS);
    const float bias = (wz_b[cc] - bn_m[cc]) * inv + bn_b[cc];

    const float4* xp = (const float4*)(x   + ((size_t)b * CH + cc) * NPIX + n0);
    float4*       op = (float4*)      (out + ((size_t)b * CH + cc) * NPIX + n0);
#pragma unroll
    for (int n4 = 0; n4 < 8; ++n4) {
        float4 xv = xp[n4];
        float4 ov;
        ov.x = acc[n4 * 4 + 0] * inv + bias + xv.x;
        ov.y = acc[n4 * 4 + 1] * inv + bias + xv.y;
        ov.z = acc[n4 * 4 + 2] * inv + bias + xv.z;
        ov.w = acc[n4 * 4 + 3] * inv + bias + xv.w;
        op[n4] = ov;
    }
}

// ---------------------------------------------------------------------------
extern "C" void kernel_launch(void* const* d_in, const int* in_sizes, int n_in,
                              void* d_out, int out_size, void* d_ws, size_t ws_size,
                              hipStream_t stream)
{
    const float* x       = (const float*)d_in[0];
    const float* g_w     = (const float*)d_in[1];
    const float* g_b     = (const float*)d_in[2];
    const float* theta_w = (const float*)d_in[3];
    const float* theta_b = (const float*)d_in[4];
    const float* phi_w   = (const float*)d_in[5];
    const float* phi_b   = (const float*)d_in[6];
    const float* wf_w    = (const float*)d_in[7];
    const float* wf_b    = (const float*)d_in[8];
    const float* wz_w    = (const float*)d_in[9];
    const float* wz_b    = (const float*)d_in[10];
    const float* bn_g    = (const float*)d_in[11];
    const float* bn_b    = (const float*)d_in[12];
    const float* bn_m    = (const float*)d_in[13];
    const float* bn_v    = (const float*)d_in[14];

    float* ws = (float*)d_ws;
    float* ta_w   = ws;                                   // 256
    float* pb_w   = ws + 256;                             // 256
    float* biases = ws + 512;                             // 4
    float* params = ws + 516;                             // 16
    float* a_arr  = ws + 532;                             // B*NPIX
    float* bsc      = a_arr + BATCH * NPIX;               // B*NPIX
    float* s_sorted = bsc + BATCH * NPIX;                 // B*NPIX
    int*   idx_sorted = (int*)(s_sorted + BATCH * NPIX);  // B*NPIX ints
    int*   bstart     = idx_sorted + BATCH * NPIX;        // B*(NB+1) ints
    float* CS1    = (float*)(bstart + BATCH * (NB + 1));  // B*100*CI
    float* CS2    = CS1 + BATCH * 100 * CI;               // B*100*CI
    unsigned short* gx16 = (unsigned short*)(CS2 + BATCH * 100 * CI); // B*NPIX*CI bf16
    unsigned int* S12 = (unsigned int*)(gx16 + (size_t)BATCH * NPIX * CI); // B*NR*CI packed

    k_fold<<<1, 256, 0, stream>>>(wf_w, theta_w, theta_b, phi_w, phi_b,
                                  ta_w, pb_w, biases);

    k_gx<<<dim3(NCHUNK, BATCH), 256, 0, stream>>>(
        x, g_w, g_b, ta_w, pb_w, biases, gx16, a_arr, bsc);

    k_bucketsort<<<BATCH, 1024, 0, stream>>>(bsc, s_sorted, idx_sorted,
                                             bstart, params);

    k_chunksum<<<dim3(NCHUNK, BATCH), 128, 0, stream>>>(
        gx16, s_sorted, idx_sorted, CS1, CS2);

    k_suffix<<<BATCH, 128, 0, stream>>>(CS1, CS2, S12);

    k_expand<<<dim3(NCHUNK, BATCH), 128, 0, stream>>>(
        gx16, s_sorted, idx_sorted, CS1, CS2, S12);

    k_final<<<dim3(NCHUNK, BATCH), 256, 0, stream>>>(
        x, a_arr, wf_b, s_sorted, idx_sorted, gx16, S12, bstart, params,
        wz_w, wz_b, bn_g, bn_b, bn_m, bn_v, (float*)d_out);
}

// Round 4
// 241.644 us; speedup vs baseline: 1.8768x; 1.0995x over previous
//
#include <hip/hip_runtime.h>
#include <cfloat>
#include <math.h>

#define BATCH 8
#define CH 256
#define CI 128
#define NPIX 3136   // 56*56
#define NCHUNK 98   // 3136/32
#define NR (NPIX + 1)       // suffix rows incl. rank==NPIX (zero row)
#define NB 4096             // buckets for the scatter sort
#define BN_EPS 1e-5f

__device__ __forceinline__ float bf2f(unsigned short u) {
    union { unsigned int i; float f; } x; x.i = ((unsigned int)u) << 16; return x.f;
}
__device__ __forceinline__ unsigned short f2bf(float f) {
    union { float f; unsigned int i; } x; x.f = f;
    unsigned int u = x.i;
    return (unsigned short)((u + 0x7FFFu + ((u >> 16) & 1u)) >> 16);  // RNE
}

// ---------------------------------------------------------------------------
// K1: fold wf_w into theta/phi weights.
// ---------------------------------------------------------------------------
__global__ __launch_bounds__(256) void k_fold(
    const float* __restrict__ wf_w,
    const float* __restrict__ theta_w, const float* __restrict__ theta_b,
    const float* __restrict__ phi_w,   const float* __restrict__ phi_b,
    float* __restrict__ ta_w, float* __restrict__ pb_w, float* __restrict__ biases)
{
    int k = threadIdx.x;  // 0..255
    float ta = 0.f, pb = 0.f;
    for (int c = 0; c < CI; ++c) {
        ta += wf_w[c]      * theta_w[c * CH + k];
        pb += wf_w[CI + c] * phi_w[c * CH + k];
    }
    ta_w[k] = ta;
    pb_w[k] = pb;
    if (k == 0) {
        float tb = 0.f, pbb = 0.f;
        for (int c = 0; c < CI; ++c) {
            tb  += wf_w[c]      * theta_b[c];
            pbb += wf_w[CI + c] * phi_b[c];
        }
        biases[0] = tb;
        biases[1] = pbb;
    }
}

// ---------------------------------------------------------------------------
// K2: per-pixel projections a[b,n], bsc[b,n] only (light, runs before sort).
// grid (98, B), block 256 = 32 pixels x 8 channel-groups of 32.
// ---------------------------------------------------------------------------
__global__ __launch_bounds__(256) void k_proj(
    const float* __restrict__ x,
    const float* __restrict__ ta_w, const float* __restrict__ pb_w,
    const float* __restrict__ biases,
    float* __restrict__ a_out, float* __restrict__ bsc_out)
{
    __shared__ float ra[8][32], rp[8][32];
    const int b  = blockIdx.y;
    const int n0 = blockIdx.x * 32;
    const int p  = threadIdx.x & 31;
    const int g  = threadIdx.x >> 5;

    float aa = 0.f, pp = 0.f;
#pragma unroll 8
    for (int cc = 0; cc < 32; ++cc) {
        int c = g * 32 + cc;
        float v = x[((size_t)b * CH + c) * NPIX + n0 + p];
        aa += ta_w[c] * v;
        pp += pb_w[c] * v;
    }
    ra[g][p] = aa; rp[g][p] = pp;
    __syncthreads();
    if (threadIdx.x < 32) {
        float sa = 0.f, sp = 0.f;
#pragma unroll
        for (int gg = 0; gg < 8; ++gg) { sa += ra[gg][threadIdx.x]; sp += rp[gg][threadIdx.x]; }
        a_out[b * NPIX + n0 + threadIdx.x]   = sa + biases[0];
        bsc_out[b * NPIX + n0 + threadIdx.x] = sp + biases[1];
    }
}

// ---------------------------------------------------------------------------
// K3: per-batch bucket scatter: min/max -> 4096-bucket histogram -> scan ->
// scatter. Outputs grouped values s_sorted, inverse permutation rankof
// (pixel -> grouped rank), bucket start table, (bmin, scale).
// grid (B), block 1024.
// ---------------------------------------------------------------------------
__global__ __launch_bounds__(1024) void k_bucketsort(
    const float* __restrict__ bsc,
    float* __restrict__ s_sorted, int* __restrict__ rankof,
    int* __restrict__ bstart, float* __restrict__ params)
{
    __shared__ float vals[NPIX];            // 12.25 KB
    __shared__ unsigned short qarr[NPIX];   // 6.1 KB
    __shared__ int hist[NB];                // 16 KB
    __shared__ int cnt[NB];                 // 16 KB
    __shared__ float red[1024];             // 4 KB (reused as psum)
    __shared__ float red2[1024];            // 4 KB
    __shared__ float sh_min, sh_scale;

    const int b = blockIdx.x, tid = threadIdx.x;

    float lmin = FLT_MAX, lmax = -FLT_MAX;
    for (int i = tid; i < NPIX; i += 1024) {
        float v = bsc[b * NPIX + i];
        vals[i] = v;
        lmin = fminf(lmin, v);
        lmax = fmaxf(lmax, v);
    }
    red[tid] = lmin; red2[tid] = lmax;
    __syncthreads();
    for (int off = 512; off > 0; off >>= 1) {
        if (tid < off) {
            red[tid]  = fminf(red[tid],  red[tid + off]);
            red2[tid] = fmaxf(red2[tid], red2[tid + off]);
        }
        __syncthreads();
    }
    if (tid == 0) {
        float mn = red[0], mx = red2[0];
        float range = mx - mn;
        float scale = (range > 0.f) ? (float)NB / range : 0.f;
        sh_min = mn; sh_scale = scale;
        params[b * 2] = mn; params[b * 2 + 1] = scale;
    }
    for (int i = tid; i < NB; i += 1024) { hist[i] = 0; cnt[i] = 0; }
    __syncthreads();

    const float bmin = sh_min, scale = sh_scale;
    for (int i = tid; i < NPIX; i += 1024) {
        int q = (int)((vals[i] - bmin) * scale);
        q = (q < 0) ? 0 : ((q > NB - 1) ? NB - 1 : q);
        qarr[i] = (unsigned short)q;
        atomicAdd(&hist[q], 1);
    }
    __syncthreads();

    // exclusive scan of hist (4 buckets per thread)
    int* psum = (int*)red;
    const int base4 = tid * 4;
    int h0 = hist[base4], h1 = hist[base4 + 1], h2 = hist[base4 + 2], h3 = hist[base4 + 3];
    psum[tid] = h0 + h1 + h2 + h3;
    __syncthreads();
    for (int off = 1; off < 1024; off <<= 1) {
        int v = psum[tid];
        int w = (tid >= off) ? psum[tid - off] : 0;
        __syncthreads();
        psum[tid] = v + w;
        __syncthreads();
    }
    int excl = (tid == 0) ? 0 : psum[tid - 1];
    hist[base4]     = excl;
    hist[base4 + 1] = excl + h0;
    hist[base4 + 2] = excl + h0 + h1;
    hist[base4 + 3] = excl + h0 + h1 + h2;
    __syncthreads();

    for (int i = tid; i < NB; i += 1024) bstart[b * (NB + 1) + i] = hist[i];
    if (tid == 0) bstart[b * (NB + 1) + NB] = NPIX;

    for (int i = tid; i < NPIX; i += 1024) {
        int q = qarr[i];
        int pos = hist[q] + atomicAdd(&cnt[q], 1);
        s_sorted[b * NPIX + pos] = vals[i];
        rankof[b * NPIX + i]     = pos;
    }
}

// ---------------------------------------------------------------------------
// K4: g-GEMM, writes rows DIRECTLY in grouped (bucket) order: gxg[rank, o].
// grid (98, B), block 256. LDS-staged x tile (256 x 32).
// ---------------------------------------------------------------------------
__global__ __launch_bounds__(256) void k_gemm(
    const float* __restrict__ x,
    const float* __restrict__ g_w, const float* __restrict__ g_b,
    const int* __restrict__ rankof,
    unsigned short* __restrict__ gxg)
{
    __shared__ float xs[CH][32];
    __shared__ int rk[32];
    const int b  = blockIdx.y;
    const int n0 = blockIdx.x * 32;
    const int tid = threadIdx.x;

    if (tid < 32) rk[tid] = rankof[b * NPIX + n0 + tid];
    for (int t = tid; t < CH * 8; t += 256) {
        int c = t >> 3, n4 = t & 7;
        const float4* src = (const float4*)(x + ((size_t)b * CH + c) * NPIX + n0);
        ((float4*)&xs[c][0])[n4] = src[n4];
    }
    __syncthreads();

    const int o  = tid & 127;
    const int nb = (tid >> 7) * 16;

    float acc[16];
#pragma unroll
    for (int i = 0; i < 16; ++i) acc[i] = 0.f;

    const float4* gw4 = (const float4*)(g_w + (size_t)o * CH);
    for (int c4 = 0; c4 < CH / 4; ++c4) {
        float4 w = gw4[c4];
        int c = c4 * 4;
#pragma unroll
        for (int i = 0; i < 16; ++i) {
            acc[i] += w.x * xs[c][nb + i] + w.y * xs[c + 1][nb + i]
                    + w.z * xs[c + 2][nb + i] + w.w * xs[c + 3][nb + i];
        }
    }
    const float gb = g_b[o];
#pragma unroll
    for (int i = 0; i < 16; ++i) {
        gxg[((size_t)b * NPIX + rk[nb + i]) * CI + o] = f2bf(acc[i] + gb);
    }
}

// ---------------------------------------------------------------------------
// K5: per-chunk sums over GROUPED rows (pure streaming, no gather).
// grid (NCHUNK, B), block 128.
// ---------------------------------------------------------------------------
__global__ __launch_bounds__(128) void k_csum(
    const unsigned short* __restrict__ gxg,
    const float* __restrict__ s_sorted,
    float* __restrict__ CS1, float* __restrict__ CS2)
{
    const int b = blockIdx.y, c = blockIdx.x, o = threadIdx.x;
    float a1 = 0.f, a2 = 0.f;
    const int base = b * NPIX + c * 32;
#pragma unroll 8
    for (int rr = 0; rr < 32; ++rr) {
        float v = bf2f(gxg[(size_t)(base + rr) * CI + o]);
        a1 += v;
        a2 += s_sorted[base + rr] * v;
    }
    CS1[(b * 100 + c) * CI + o] = a1;
    CS2[(b * 100 + c) * CI + o] = a2;
}

// ---------------------------------------------------------------------------
// K6: suffix scan over 98 chunks; CS1 by threads 0-127, CS2 by 128-255.
// Also zeroes CS rows 98/99 and S12 row NPIX. grid (B), block 256.
// ---------------------------------------------------------------------------
__global__ __launch_bounds__(256) void k_suffix(
    float* __restrict__ CS1, float* __restrict__ CS2,
    unsigned int* __restrict__ S12)
{
    const int b = blockIdx.x;
    const int half = threadIdx.x >> 7, o = threadIdx.x & 127;
    float* __restrict__ CS = half ? CS2 : CS1;
    float acc = 0.f;
    for (int c = NCHUNK - 1; c >= 0; --c) {
        size_t idx = (size_t)(b * 100 + c) * CI + o;
        acc += CS[idx];
        CS[idx] = acc;
    }
    CS[(size_t)(b * 100 + 98) * CI + o] = 0.f;
    CS[(size_t)(b * 100 + 99) * CI + o] = 0.f;
    if (half == 0) S12[((size_t)b * NR + NPIX) * CI + o] = 0u;
}

// ---------------------------------------------------------------------------
// K7: expand to per-rank suffix rows, packed bf16 (S1 lo, S2 hi) — streaming.
// grid (NCHUNK, B), block 128.
// ---------------------------------------------------------------------------
__global__ __launch_bounds__(128) void k_expand(
    const unsigned short* __restrict__ gxg,
    const float* __restrict__ s_sorted,
    const float* __restrict__ CS1, const float* __restrict__ CS2,
    unsigned int* __restrict__ S12)
{
    const int b = blockIdx.y, c = blockIdx.x, o = threadIdx.x;
    float a1 = CS1[(size_t)(b * 100 + c + 1) * CI + o];
    float a2 = CS2[(size_t)(b * 100 + c + 1) * CI + o];
    const int base = b * NPIX + c * 32;
#pragma unroll 8
    for (int rr = 31; rr >= 0; --rr) {
        float v = bf2f(gxg[(size_t)(base + rr) * CI + o]);
        a1 += v;
        a2 += s_sorted[base + rr] * v;
        unsigned int pack = (unsigned int)f2bf(a1) | ((unsigned int)f2bf(a2) << 16);
        S12[((size_t)b * NR + c * 32 + rr) * CI + o] = pack;
    }
}

// ---------------------------------------------------------------------------
// K8 (fused): rounded bucket lookup -> y row via ONE packed suffix-row load
// (no gather, no inner loop) -> wz GEMM -> BN -> residual -> out.
// grid (98, B), block 256.
// ---------------------------------------------------------------------------
__global__ __launch_bounds__(256) void k_final(
    const float* __restrict__ x,
    const float* __restrict__ a_arr, const float* __restrict__ wf_b,
    const unsigned int* __restrict__ S12,
    const int* __restrict__ bstart, const float* __restrict__ params,
    const float* __restrict__ wz_w, const float* __restrict__ wz_b,
    const float* __restrict__ bn_g, const float* __restrict__ bn_b,
    const float* __restrict__ bn_m, const float* __restrict__ bn_v,
    float* __restrict__ out)
{
    __shared__ float ys[32][CI];
    __shared__ int   rs[32];
    __shared__ float ts[32];

    const int b = blockIdx.y;
    const int n0 = blockIdx.x * 32;
    const int tid = threadIdx.x;

    if (tid < 32) {
        float t = a_arr[b * NPIX + n0 + tid] + wf_b[0];
        float bmin = params[b * 2], scale = params[b * 2 + 1];
        float fq = (-t - bmin) * scale;
        int kb = (int)(fq + 0.5f);           // round to nearest bucket edge
        kb = (kb < 0) ? 0 : ((kb > NB) ? NB : kb);
        rs[tid] = bstart[b * (NB + 1) + kb]; // bstart[NB] == NPIX (zero row)
        ts[tid] = t;
    }
    __syncthreads();

    const int o = tid & 127;
    const int h = tid >> 7;
    const float invN = 1.0f / (float)NPIX;

    // 16 independent packed loads, no control flow -> fully pipelined
    unsigned int packs[16];
#pragma unroll
    for (int i = 0; i < 16; ++i) {
        int n = h * 16 + i;
        packs[i] = S12[((size_t)b * NR + rs[n]) * CI + o];
    }
#pragma unroll
    for (int i = 0; i < 16; ++i) {
        int n = h * 16 + i;
        float S1 = bf2f((unsigned short)(packs[i] & 0xFFFFu));
        float S2 = bf2f((unsigned short)(packs[i] >> 16));
        ys[n][o] = (ts[n] * S1 + S2) * invN;
    }
    __syncthreads();

    // wz GEMM + BN + residual: one thread per output channel
    const int cc = tid;  // 0..255
    float acc[32];
#pragma unroll
    for (int n = 0; n < 32; ++n) acc[n] = 0.f;

    const float4* wz4 = (const float4*)(wz_w + (size_t)cc * CI);
    for (int o4 = 0; o4 < CI / 4; ++o4) {
        float4 w = wz4[o4];
#pragma unroll
        for (int n = 0; n < 32; ++n) {
            float4 yv = *((const float4*)&ys[n][o4 * 4]);
            acc[n] += w.x * yv.x + w.y * yv.y + w.z * yv.z + w.w * yv.w;
        }
    }

    const float inv  = bn_g[cc] * rsqrtf(bn_v[cc] + BN_EPS);
    const float bias = (wz_b[cc] - bn_m[cc]) * inv + bn_b[cc];

    const float4* xp = (const float4*)(x   + ((size_t)b * CH + cc) * NPIX + n0);
    float4*       op = (float4*)      (out + ((size_t)b * CH + cc) * NPIX + n0);
#pragma unroll
    for (int n4 = 0; n4 < 8; ++n4) {
        float4 xv = xp[n4];
        float4 ov;
        ov.x = acc[n4 * 4 + 0] * inv + bias + xv.x;
        ov.y = acc[n4 * 4 + 1] * inv + bias + xv.y;
        ov.z = acc[n4 * 4 + 2] * inv + bias + xv.z;
        ov.w = acc[n4 * 4 + 3] * inv + bias + xv.w;
        op[n4] = ov;
    }
}

// ---------------------------------------------------------------------------
extern "C" void kernel_launch(void* const* d_in, const int* in_sizes, int n_in,
                              void* d_out, int out_size, void* d_ws, size_t ws_size,
                              hipStream_t stream)
{
    const float* x       = (const float*)d_in[0];
    const float* g_w     = (const float*)d_in[1];
    const float* g_b     = (const float*)d_in[2];
    const float* theta_w = (const float*)d_in[3];
    const float* theta_b = (const float*)d_in[4];
    const float* phi_w   = (const float*)d_in[5];
    const float* phi_b   = (const float*)d_in[6];
    const float* wf_w    = (const float*)d_in[7];
    const float* wf_b    = (const float*)d_in[8];
    const float* wz_w    = (const float*)d_in[9];
    const float* wz_b    = (const float*)d_in[10];
    const float* bn_g    = (const float*)d_in[11];
    const float* bn_b    = (const float*)d_in[12];
    const float* bn_m    = (const float*)d_in[13];
    const float* bn_v    = (const float*)d_in[14];

    float* ws = (float*)d_ws;
    float* ta_w   = ws;                                   // 256
    float* pb_w   = ws + 256;                             // 256
    float* biases = ws + 512;                             // 4
    float* params = ws + 516;                             // 16
    float* a_arr  = ws + 532;                             // B*NPIX
    float* bsc      = a_arr + BATCH * NPIX;               // B*NPIX
    float* s_sorted = bsc + BATCH * NPIX;                 // B*NPIX
    int*   rankof   = (int*)(s_sorted + BATCH * NPIX);    // B*NPIX ints
    int*   bstart   = rankof + BATCH * NPIX;              // B*(NB+1) ints
    float* CS1    = (float*)(bstart + BATCH * (NB + 1));  // B*100*CI
    float* CS2    = CS1 + BATCH * 100 * CI;               // B*100*CI
    unsigned short* gxg = (unsigned short*)(CS2 + BATCH * 100 * CI); // B*NPIX*CI bf16
    unsigned int* S12 = (unsigned int*)(gxg + (size_t)BATCH * NPIX * CI); // B*NR*CI

    k_fold<<<1, 256, 0, stream>>>(wf_w, theta_w, theta_b, phi_w, phi_b,
                                  ta_w, pb_w, biases);

    k_proj<<<dim3(NCHUNK, BATCH), 256, 0, stream>>>(
        x, ta_w, pb_w, biases, a_arr, bsc);

    k_bucketsort<<<BATCH, 1024, 0, stream>>>(bsc, s_sorted, rankof,
                                             bstart, params);

    k_gemm<<<dim3(NCHUNK, BATCH), 256, 0, stream>>>(
        x, g_w, g_b, rankof, gxg);

    k_csum<<<dim3(NCHUNK, BATCH), 128, 0, stream>>>(
        gxg, s_sorted, CS1, CS2);

    k_suffix<<<BATCH, 256, 0, stream>>>(CS1, CS2, S12);

    k_expand<<<dim3(NCHUNK, BATCH), 128, 0, stream>>>(
        gxg, s_sorted, CS1, CS2, S12);

    k_final<<<dim3(NCHUNK, BATCH), 256, 0, stream>>>(
        x, a_arr, wf_b, S12, bstart, params,
        wz_w, wz_b, bn_g, bn_b, bn_m, bn_v, (float*)d_out);
}

// Round 5
// 171.026 us; speedup vs baseline: 2.6518x; 1.4129x over previous
//
#include <hip/hip_runtime.h>
#include <cfloat>
#include <math.h>

#define BATCH 8
#define CH 256
#define CI 128
#define NPIX 3136   // 56*56
#define NCHUNK 98   // 3136/32
#define NB 4096     // buckets for the scatter sort
#define BN_EPS 1e-5f

typedef __attribute__((ext_vector_type(8))) short bf16x8;   // 8 bf16 in 4 VGPRs
typedef __attribute__((ext_vector_type(4))) float f32x4;

__device__ __forceinline__ float bf2f(unsigned short u) {
    union { unsigned int i; float f; } x; x.i = ((unsigned int)u) << 16; return x.f;
}
__device__ __forceinline__ unsigned short f2bf(float f) {
    union { float f; unsigned int i; } x; x.f = f;
    unsigned int u = x.i;
    return (unsigned short)((u + 0x7FFFu + ((u >> 16) & 1u)) >> 16);  // RNE
}

// ---------------------------------------------------------------------------
// K1: block 0: fold wf into theta/phi weights (+biases).
// blocks 1-8:  swizzle g_w^T into bf16 B-fragments  (K=256 -> 8 ksteps, N=128 -> 8 ntiles)
// blocks 9-16: swizzle wz_w^T into bf16 B-fragments (K=128 -> 4 ksteps, N=256 -> 16 ntiles)
// B-frag layout per MFMA 16x16x32: lane l, j: B[k=(l>>4)*8+j][n=l&15]
// ---------------------------------------------------------------------------
__global__ __launch_bounds__(256) void k_fold(
    const float* __restrict__ wf_w,
    const float* __restrict__ theta_w, const float* __restrict__ theta_b,
    const float* __restrict__ phi_w,   const float* __restrict__ phi_b,
    const float* __restrict__ g_w,     const float* __restrict__ wz_w,
    float* __restrict__ ta_w, float* __restrict__ pb_w, float* __restrict__ biases,
    unsigned short* __restrict__ Bfrag_g, unsigned short* __restrict__ Bfrag_w)
{
    const int bk = blockIdx.x, tid = threadIdx.x;
    if (bk == 0) {
        float ta = 0.f, pb = 0.f;
        for (int c = 0; c < CI; ++c) {
            ta += wf_w[c]      * theta_w[c * CH + tid];
            pb += wf_w[CI + c] * phi_w[c * CH + tid];
        }
        ta_w[tid] = ta;
        pb_w[tid] = pb;
        if (tid == 0) {
            float tb = 0.f, pbb = 0.f;
            for (int c = 0; c < CI; ++c) {
                tb  += wf_w[c]      * theta_b[c];
                pbb += wf_w[CI + c] * phi_b[c];
            }
            biases[0] = tb;
            biases[1] = pbb;
        }
    } else if (bk <= 8) {
        const int base_pair = (bk - 1) * 8;
        for (int e = tid; e < 4096; e += 256) {
            int pp = e >> 9, lane = (e >> 3) & 63, j = e & 7;
            int pair = base_pair + pp;
            int ks = pair >> 3, nt = pair & 7;
            int k = ks * 32 + (lane >> 4) * 8 + j;
            int n = nt * 16 + (lane & 15);
            Bfrag_g[(size_t)pair * 512 + lane * 8 + j] = f2bf(g_w[n * CH + k]);
        }
    } else {
        const int base_pair = (bk - 9) * 8;
        for (int e = tid; e < 4096; e += 256) {
            int pp = e >> 9, lane = (e >> 3) & 63, j = e & 7;
            int pair = base_pair + pp;
            int ks = pair >> 4, nt = pair & 15;
            int k = ks * 32 + (lane >> 4) * 8 + j;
            int n = nt * 16 + (lane & 15);
            Bfrag_w[(size_t)pair * 512 + lane * 8 + j] = f2bf(wz_w[n * CI + k]);
        }
    }
}

// ---------------------------------------------------------------------------
// K2 (fused): x -> LDS (fp32) -> a/bsc projections (fp32) + x transposed to
// bf16 xT[b][pixel][c] for the MFMA GEMM. grid (98, B), block 256.
// ---------------------------------------------------------------------------
__global__ __launch_bounds__(256) void k_conv(
    const float* __restrict__ x,
    const float* __restrict__ ta_w, const float* __restrict__ pb_w,
    const float* __restrict__ biases,
    float* __restrict__ a_out, float* __restrict__ bsc_out,
    unsigned short* __restrict__ xT)
{
    __shared__ float xs[CH][36];   // pad 36: float4-aligned rows, conflict-free cols
    __shared__ float ra[8][32], rp[8][32];
    const int b  = blockIdx.y;
    const int n0 = blockIdx.x * 32;
    const int tid = threadIdx.x;

    for (int t = tid; t < CH * 8; t += 256) {
        int c = t >> 3, n4 = t & 7;
        const float4* src = (const float4*)(x + ((size_t)b * CH + c) * NPIX + n0);
        *((float4*)&xs[c][n4 * 4]) = src[n4];
    }
    __syncthreads();

    const int p = tid & 31;        // pixel
    const int g = tid >> 5;        // channel group (32 c each)

    // a/bsc partial dots
    {
        float aa = 0.f, pp = 0.f;
#pragma unroll 8
        for (int cc = 0; cc < 32; ++cc) {
            int c = g * 32 + cc;
            float v = xs[c][p];
            aa += ta_w[c] * v;
            pp += pb_w[c] * v;
        }
        ra[g][p] = aa; rp[g][p] = pp;
    }

    // bf16 transpose: thread (pixel p, c-range g*32..+32) -> xT row
    {
        const int cbase = g * 32;
        unsigned int wbuf[16];
#pragma unroll
        for (int q = 0; q < 16; ++q) {
            float lo = xs[cbase + 2 * q][p];
            float hi = xs[cbase + 2 * q + 1][p];
            wbuf[q] = (unsigned int)f2bf(lo) | ((unsigned int)f2bf(hi) << 16);
        }
        uint4* dst = (uint4*)(xT + ((size_t)(b * NPIX + n0 + p)) * CH + cbase);
#pragma unroll
        for (int v4 = 0; v4 < 4; ++v4) {
            uint4 u;
            u.x = wbuf[4 * v4]; u.y = wbuf[4 * v4 + 1];
            u.z = wbuf[4 * v4 + 2]; u.w = wbuf[4 * v4 + 3];
            dst[v4] = u;
        }
    }
    __syncthreads();

    if (tid < 32) {
        float sa = 0.f, sp = 0.f;
#pragma unroll
        for (int gg = 0; gg < 8; ++gg) { sa += ra[gg][tid]; sp += rp[gg][tid]; }
        a_out[b * NPIX + n0 + tid]   = sa + biases[0];
        bsc_out[b * NPIX + n0 + tid] = sp + biases[1];
    }
}

// ---------------------------------------------------------------------------
// K3: per-batch bucket scatter (unchanged from R4, proven).
// grid (B), block 1024.
// ---------------------------------------------------------------------------
__global__ __launch_bounds__(1024) void k_bucketsort(
    const float* __restrict__ bsc,
    float* __restrict__ s_sorted, int* __restrict__ rankof,
    int* __restrict__ bstart, float* __restrict__ params)
{
    __shared__ float vals[NPIX];
    __shared__ unsigned short qarr[NPIX];
    __shared__ int hist[NB];
    __shared__ int cnt[NB];
    __shared__ float red[1024];
    __shared__ float red2[1024];
    __shared__ float sh_min, sh_scale;

    const int b = blockIdx.x, tid = threadIdx.x;

    float lmin = FLT_MAX, lmax = -FLT_MAX;
    for (int i = tid; i < NPIX; i += 1024) {
        float v = bsc[b * NPIX + i];
        vals[i] = v;
        lmin = fminf(lmin, v);
        lmax = fmaxf(lmax, v);
    }
    red[tid] = lmin; red2[tid] = lmax;
    __syncthreads();
    for (int off = 512; off > 0; off >>= 1) {
        if (tid < off) {
            red[tid]  = fminf(red[tid],  red[tid + off]);
            red2[tid] = fmaxf(red2[tid], red2[tid + off]);
        }
        __syncthreads();
    }
    if (tid == 0) {
        float mn = red[0], mx = red2[0];
        float range = mx - mn;
        float scale = (range > 0.f) ? (float)NB / range : 0.f;
        sh_min = mn; sh_scale = scale;
        params[b * 2] = mn; params[b * 2 + 1] = scale;
    }
    for (int i = tid; i < NB; i += 1024) { hist[i] = 0; cnt[i] = 0; }
    __syncthreads();

    const float bmin = sh_min, scale = sh_scale;
    for (int i = tid; i < NPIX; i += 1024) {
        int q = (int)((vals[i] - bmin) * scale);
        q = (q < 0) ? 0 : ((q > NB - 1) ? NB - 1 : q);
        qarr[i] = (unsigned short)q;
        atomicAdd(&hist[q], 1);
    }
    __syncthreads();

    int* psum = (int*)red;
    const int base4 = tid * 4;
    int h0 = hist[base4], h1 = hist[base4 + 1], h2 = hist[base4 + 2], h3 = hist[base4 + 3];
    psum[tid] = h0 + h1 + h2 + h3;
    __syncthreads();
    for (int off = 1; off < 1024; off <<= 1) {
        int v = psum[tid];
        int w = (tid >= off) ? psum[tid - off] : 0;
        __syncthreads();
        psum[tid] = v + w;
        __syncthreads();
    }
    int excl = (tid == 0) ? 0 : psum[tid - 1];
    hist[base4]     = excl;
    hist[base4 + 1] = excl + h0;
    hist[base4 + 2] = excl + h0 + h1;
    hist[base4 + 3] = excl + h0 + h1 + h2;
    __syncthreads();

    for (int i = tid; i < NB; i += 1024) bstart[b * (NB + 1) + i] = hist[i];
    if (tid == 0) bstart[b * (NB + 1) + NB] = NPIX;

    for (int i = tid; i < NPIX; i += 1024) {
        int q = qarr[i];
        int pos = hist[q] + atomicAdd(&cnt[q], 1);
        s_sorted[b * NPIX + pos] = vals[i];
        rankof[b * NPIX + i]     = pos;
    }
}

// ---------------------------------------------------------------------------
// K4: g-GEMM via MFMA bf16. D[px(32) x o(128)] = xT_tile(32x256) * g_wT(256x128).
// Writes rows in grouped (bucket) order via rankof. grid (98, B), block 256.
// ---------------------------------------------------------------------------
__global__ __launch_bounds__(256) void k_gemm(
    const unsigned short* __restrict__ xT,
    const unsigned short* __restrict__ Bfrag_g,
    const float* __restrict__ g_b,
    const int* __restrict__ rankof,
    unsigned short* __restrict__ gxg)
{
    __shared__ unsigned short xs[32 * 264];   // pad 264 -> conflict-free A-frags
    __shared__ unsigned short gout[32 * 136]; // pad 136
    __shared__ int rk[32];

    const int b  = blockIdx.y;
    const int n0 = blockIdx.x * 32;
    const int tid = threadIdx.x;

    if (tid < 32) rk[tid] = rankof[b * NPIX + n0 + tid];
    {
        const int n = tid >> 3, ch = tid & 7;
        const uint4* src = (const uint4*)(xT + ((size_t)(b * NPIX + n0 + n)) * CH + ch * 32);
        uint4* dst = (uint4*)(&xs[n * 264 + ch * 32]);
        dst[0] = src[0]; dst[1] = src[1]; dst[2] = src[2]; dst[3] = src[3];
    }
    __syncthreads();

    const int w = tid >> 6, l = tid & 63, lm = l & 15, lq = l >> 4;
    f32x4 acc[2][2];
#pragma unroll
    for (int mi = 0; mi < 2; ++mi)
#pragma unroll
        for (int ni = 0; ni < 2; ++ni) acc[mi][ni] = (f32x4){0.f, 0.f, 0.f, 0.f};

#pragma unroll
    for (int ks = 0; ks < 8; ++ks) {
        bf16x8 a0 = *(const bf16x8*)&xs[lm * 264 + ks * 32 + lq * 8];
        bf16x8 a1 = *(const bf16x8*)&xs[(16 + lm) * 264 + ks * 32 + lq * 8];
        bf16x8 b0 = *(const bf16x8*)(Bfrag_g + ((size_t)(ks * 8 + w * 2) * 64 + l) * 8);
        bf16x8 b1 = *(const bf16x8*)(Bfrag_g + ((size_t)(ks * 8 + w * 2 + 1) * 64 + l) * 8);
        acc[0][0] = __builtin_amdgcn_mfma_f32_16x16x32_bf16(a0, b0, acc[0][0], 0, 0, 0);
        acc[0][1] = __builtin_amdgcn_mfma_f32_16x16x32_bf16(a0, b1, acc[0][1], 0, 0, 0);
        acc[1][0] = __builtin_amdgcn_mfma_f32_16x16x32_bf16(a1, b0, acc[1][0], 0, 0, 0);
        acc[1][1] = __builtin_amdgcn_mfma_f32_16x16x32_bf16(a1, b1, acc[1][1], 0, 0, 0);
    }

#pragma unroll
    for (int mi = 0; mi < 2; ++mi)
#pragma unroll
        for (int ni = 0; ni < 2; ++ni) {
            int o = w * 32 + ni * 16 + lm;
            float gb = g_b[o];
#pragma unroll
            for (int r = 0; r < 4; ++r) {
                int m = mi * 16 + lq * 4 + r;
                gout[m * 136 + o] = f2bf(acc[mi][ni][r] + gb);
            }
        }
    __syncthreads();

    {
        const int n = tid >> 3, ch = tid & 7;
        const uint4* s = (const uint4*)&gout[n * 136 + ch * 16];
        uint4* d = (uint4*)(gxg + ((size_t)(b * NPIX + rk[n])) * CI + ch * 16);
        d[0] = s[0]; d[1] = s[1];
    }
}

// ---------------------------------------------------------------------------
// K5: per-chunk sums over grouped rows (streaming). grid (NCHUNK, B), blk 128.
// ---------------------------------------------------------------------------
__global__ __launch_bounds__(128) void k_csum(
    const unsigned short* __restrict__ gxg,
    const float* __restrict__ s_sorted,
    float* __restrict__ CS1, float* __restrict__ CS2)
{
    const int b = blockIdx.y, c = blockIdx.x, o = threadIdx.x;
    float a1 = 0.f, a2 = 0.f;
    const int base = b * NPIX + c * 32;
#pragma unroll 8
    for (int rr = 0; rr < 32; ++rr) {
        float v = bf2f(gxg[(size_t)(base + rr) * CI + o]);
        a1 += v;
        a2 += s_sorted[base + rr] * v;
    }
    CS1[(b * 100 + c) * CI + o] = a1;
    CS2[(b * 100 + c) * CI + o] = a2;
}

// ---------------------------------------------------------------------------
// K6: suffix scan over 98 chunks, LDS-staged (coalesced load, LDS-latency
// scan, coalesced store). Zeroes rows 98/99. grid (B), block 256.
// ---------------------------------------------------------------------------
__global__ __launch_bounds__(256) void k_suffix(
    float* __restrict__ CS1, float* __restrict__ CS2)
{
    __shared__ float buf[NCHUNK * CI];   // 49 KB
    const int b = blockIdx.x, tid = threadIdx.x;

    for (int pass = 0; pass < 2; ++pass) {
        float* __restrict__ CS = pass ? CS2 : CS1;
        for (int i = tid; i < NCHUNK * CI; i += 256) buf[i] = CS[b * 100 * CI + i];
        __syncthreads();
        if (tid < CI) {
            float acc = 0.f;
            for (int c = NCHUNK - 1; c >= 0; --c) {
                acc += buf[c * CI + tid];
                buf[c * CI + tid] = acc;
            }
        }
        __syncthreads();
        for (int i = tid; i < NCHUNK * CI; i += 256) CS[b * 100 * CI + i] = buf[i];
        if (tid < CI) {
            CS[(b * 100 + 98) * CI + tid] = 0.f;
            CS[(b * 100 + 99) * CI + tid] = 0.f;
        }
        __syncthreads();
    }
}

// ---------------------------------------------------------------------------
// K7 (fused): bucket lookup -> chunk-rounded rank -> y row from L2-resident
// CS tables -> MFMA wz-GEMM -> BN -> residual -> out. grid (98, B), blk 256.
// ---------------------------------------------------------------------------
__global__ __launch_bounds__(256) void k_final(
    const float* __restrict__ x,
    const float* __restrict__ a_arr, const float* __restrict__ wf_b,
    const float* __restrict__ CS1, const float* __restrict__ CS2,
    const int* __restrict__ bstart, const float* __restrict__ params,
    const unsigned short* __restrict__ Bfrag_w,
    const float* __restrict__ wz_b,
    const float* __restrict__ bn_g, const float* __restrict__ bn_b,
    const float* __restrict__ bn_m, const float* __restrict__ bn_v,
    float* __restrict__ out)
{
    __shared__ unsigned short ys[32 * 136];  // bf16 y tile, pad 136
    __shared__ float Df[32 * 260];           // fp32 D tile, pad 260
    __shared__ int   rs[32];
    __shared__ float ts[32];

    const int b = blockIdx.y;
    const int n0 = blockIdx.x * 32;
    const int tid = threadIdx.x;

    if (tid < 32) {
        float t = a_arr[b * NPIX + n0 + tid] + wf_b[0];
        float bmin = params[b * 2], scale = params[b * 2 + 1];
        float fq = (-t - bmin) * scale;
        int kb = (int)(fq + 0.5f);
        kb = (kb < 0) ? 0 : ((kb > NB) ? NB : kb);
        int r = bstart[b * (NB + 1) + kb];
        int cstar = (r + 16) >> 5;           // nearest chunk boundary, 0..98
        cstar = (cstar > 98) ? 98 : cstar;
        rs[tid] = cstar;
        ts[tid] = t;
    }
    __syncthreads();

    const int o = tid & 127;
    const int h = tid >> 7;
    const float invN = 1.0f / (float)NPIX;

#pragma unroll 4
    for (int i = 0; i < 16; ++i) {
        int n = h * 16 + i;
        int cb = (b * 100 + rs[n]) * CI + o;
        float S1 = CS1[cb], S2 = CS2[cb];
        ys[n * 136 + o] = f2bf((ts[n] * S1 + S2) * invN);
    }
    __syncthreads();

    // MFMA: D[px(32) x cc(256)] = ys(32x128) * wz_wT(128x256)
    const int w = tid >> 6, l = tid & 63, lm = l & 15, lq = l >> 4;
    f32x4 acc[2][4];
#pragma unroll
    for (int mi = 0; mi < 2; ++mi)
#pragma unroll
        for (int ni = 0; ni < 4; ++ni) acc[mi][ni] = (f32x4){0.f, 0.f, 0.f, 0.f};

#pragma unroll
    for (int ks = 0; ks < 4; ++ks) {
        bf16x8 a0 = *(const bf16x8*)&ys[lm * 136 + ks * 32 + lq * 8];
        bf16x8 a1 = *(const bf16x8*)&ys[(16 + lm) * 136 + ks * 32 + lq * 8];
#pragma unroll
        for (int ni = 0; ni < 4; ++ni) {
            bf16x8 bb = *(const bf16x8*)(Bfrag_w + ((size_t)(ks * 16 + w * 4 + ni) * 64 + l) * 8);
            acc[0][ni] = __builtin_amdgcn_mfma_f32_16x16x32_bf16(a0, bb, acc[0][ni], 0, 0, 0);
            acc[1][ni] = __builtin_amdgcn_mfma_f32_16x16x32_bf16(a1, bb, acc[1][ni], 0, 0, 0);
        }
    }

#pragma unroll
    for (int mi = 0; mi < 2; ++mi)
#pragma unroll
        for (int ni = 0; ni < 4; ++ni) {
            int cc = w * 64 + ni * 16 + lm;
#pragma unroll
            for (int r = 0; r < 4; ++r) {
                int m = mi * 16 + lq * 4 + r;
                Df[m * 260 + cc] = acc[mi][ni][r];
            }
        }
    __syncthreads();

    // epilogue: one thread per output channel
    const int cc = tid;
    const float inv  = bn_g[cc] * rsqrtf(bn_v[cc] + BN_EPS);
    const float bias = (wz_b[cc] - bn_m[cc]) * inv + bn_b[cc];

    const float4* xp = (const float4*)(x   + ((size_t)b * CH + cc) * NPIX + n0);
    float4*       op = (float4*)      (out + ((size_t)b * CH + cc) * NPIX + n0);
#pragma unroll
    for (int n4 = 0; n4 < 8; ++n4) {
        float4 xv = xp[n4];
        float4 ov;
        ov.x = Df[(n4 * 4 + 0) * 260 + cc] * inv + bias + xv.x;
        ov.y = Df[(n4 * 4 + 1) * 260 + cc] * inv + bias + xv.y;
        ov.z = Df[(n4 * 4 + 2) * 260 + cc] * inv + bias + xv.z;
        ov.w = Df[(n4 * 4 + 3) * 260 + cc] * inv + bias + xv.w;
        op[n4] = ov;
    }
}

// ---------------------------------------------------------------------------
extern "C" void kernel_launch(void* const* d_in, const int* in_sizes, int n_in,
                              void* d_out, int out_size, void* d_ws, size_t ws_size,
                              hipStream_t stream)
{
    const float* x       = (const float*)d_in[0];
    const float* g_w     = (const float*)d_in[1];
    const float* g_b     = (const float*)d_in[2];
    const float* theta_w = (const float*)d_in[3];
    const float* theta_b = (const float*)d_in[4];
    const float* phi_w   = (const float*)d_in[5];
    const float* phi_b   = (const float*)d_in[6];
    const float* wf_w    = (const float*)d_in[7];
    const float* wf_b    = (const float*)d_in[8];
    const float* wz_w    = (const float*)d_in[9];
    const float* wz_b    = (const float*)d_in[10];
    const float* bn_g    = (const float*)d_in[11];
    const float* bn_b    = (const float*)d_in[12];
    const float* bn_m    = (const float*)d_in[13];
    const float* bn_v    = (const float*)d_in[14];

    float* ws = (float*)d_ws;
    float* ta_w   = ws;                                    // 256
    float* pb_w   = ws + 256;                              // 256
    float* biases = ws + 512;                              // 4
    float* params = ws + 516;                              // 16
    float* a_arr  = ws + 532;                              // 25088
    float* bsc      = a_arr + BATCH * NPIX;                // 25088
    float* s_sorted = bsc + BATCH * NPIX;                  // 25088
    int*   rankof   = (int*)(s_sorted + BATCH * NPIX);     // 25088
    int*   bstart   = rankof + BATCH * NPIX;               // 8*4097 = 32776
    float* CS1    = (float*)(bstart + BATCH * (NB + 1));   // 102400
    float* CS2    = CS1 + BATCH * 100 * CI;                // 102400
    unsigned short* Bfrag_g = (unsigned short*)(CS2 + BATCH * 100 * CI); // 32768
    unsigned short* Bfrag_w = Bfrag_g + 32768;             // 32768
    unsigned short* gxg = Bfrag_w + 32768;                 // 8*3136*128 bf16
    unsigned short* xT  = gxg + (size_t)BATCH * NPIX * CI; // 8*3136*256 bf16

    k_fold<<<17, 256, 0, stream>>>(wf_w, theta_w, theta_b, phi_w, phi_b,
                                   g_w, wz_w, ta_w, pb_w, biases,
                                   Bfrag_g, Bfrag_w);

    k_conv<<<dim3(NCHUNK, BATCH), 256, 0, stream>>>(
        x, ta_w, pb_w, biases, a_arr, bsc, xT);

    k_bucketsort<<<BATCH, 1024, 0, stream>>>(bsc, s_sorted, rankof,
                                             bstart, params);

    k_gemm<<<dim3(NCHUNK, BATCH), 256, 0, stream>>>(
        xT, Bfrag_g, g_b, rankof, gxg);

    k_csum<<<dim3(NCHUNK, BATCH), 128, 0, stream>>>(
        gxg, s_sorted, CS1, CS2);

    k_suffix<<<BATCH, 256, 0, stream>>>(CS1, CS2);

    k_final<<<dim3(NCHUNK, BATCH), 256, 0, stream>>>(
        x, a_arr, wf_b, CS1, CS2, bstart, params, Bfrag_w,
        wz_b, bn_g, bn_b, bn_m, bn_v, (float*)d_out);
}

// Round 6
// 161.153 us; speedup vs baseline: 2.8142x; 1.0613x over previous
//
#include <hip/hip_runtime.h>
#include <cfloat>
#include <math.h>

#define BATCH 8
#define CH 256
#define CI 128
#define NPIX 3136   // 56*56
#define NCHUNK 98   // 3136/32
#define NB 4096     // buckets for the scatter sort
#define BN_EPS 1e-5f

typedef __attribute__((ext_vector_type(8))) short bf16x8;   // 8 bf16 in 4 VGPRs
typedef __attribute__((ext_vector_type(4))) float f32x4;

__device__ __forceinline__ float bf2f(unsigned short u) {
    union { unsigned int i; float f; } x; x.i = ((unsigned int)u) << 16; return x.f;
}
__device__ __forceinline__ unsigned short f2bf(float f) {
    union { float f; unsigned int i; } x; x.f = f;
    unsigned int u = x.i;
    return (unsigned short)((u + 0x7FFFu + ((u >> 16) & 1u)) >> 16);  // RNE
}

// ---------------------------------------------------------------------------
// K1: block 0: fold wf into theta/phi weights (+biases).
// blocks 1-8:  swizzle g_w^T into bf16 B-fragments  (K=256, N=128)
// blocks 9-16: swizzle wz_w^T into bf16 B-fragments (K=128, N=256)
// B-frag layout per MFMA 16x16x32: lane l, j: B[k=(l>>4)*8+j][n=l&15]
// ---------------------------------------------------------------------------
__global__ __launch_bounds__(256) void k_fold(
    const float* __restrict__ wf_w,
    const float* __restrict__ theta_w, const float* __restrict__ theta_b,
    const float* __restrict__ phi_w,   const float* __restrict__ phi_b,
    const float* __restrict__ g_w,     const float* __restrict__ wz_w,
    float* __restrict__ ta_w, float* __restrict__ pb_w, float* __restrict__ biases,
    unsigned short* __restrict__ Bfrag_g, unsigned short* __restrict__ Bfrag_w)
{
    const int bk = blockIdx.x, tid = threadIdx.x;
    if (bk == 0) {
        float ta = 0.f, pb = 0.f;
        for (int c = 0; c < CI; ++c) {
            ta += wf_w[c]      * theta_w[c * CH + tid];
            pb += wf_w[CI + c] * phi_w[c * CH + tid];
        }
        ta_w[tid] = ta;
        pb_w[tid] = pb;
        if (tid == 0) {
            float tb = 0.f, pbb = 0.f;
            for (int c = 0; c < CI; ++c) {
                tb  += wf_w[c]      * theta_b[c];
                pbb += wf_w[CI + c] * phi_b[c];
            }
            biases[0] = tb;
            biases[1] = pbb;
        }
    } else if (bk <= 8) {
        const int base_pair = (bk - 1) * 8;
        for (int e = tid; e < 4096; e += 256) {
            int pp = e >> 9, lane = (e >> 3) & 63, j = e & 7;
            int pair = base_pair + pp;
            int ks = pair >> 3, nt = pair & 7;
            int k = ks * 32 + (lane >> 4) * 8 + j;
            int n = nt * 16 + (lane & 15);
            Bfrag_g[(size_t)pair * 512 + lane * 8 + j] = f2bf(g_w[n * CH + k]);
        }
    } else {
        const int base_pair = (bk - 9) * 8;
        for (int e = tid; e < 4096; e += 256) {
            int pp = e >> 9, lane = (e >> 3) & 63, j = e & 7;
            int pair = base_pair + pp;
            int ks = pair >> 4, nt = pair & 15;
            int k = ks * 32 + (lane >> 4) * 8 + j;
            int n = nt * 16 + (lane & 15);
            Bfrag_w[(size_t)pair * 512 + lane * 8 + j] = f2bf(wz_w[n * CI + k]);
        }
    }
}

// ---------------------------------------------------------------------------
// K2 (fused conv+gemm): x tile -> LDS fp32 -> {a/bsc dots, bf16 transpose}
// -> MFMA with g_w B-frags -> gxg in PIXEL order (coalesced, no scatter).
// grid (98, B), block 256. gout aliases the dead fp32 tile (LDS reuse).
// ---------------------------------------------------------------------------
__global__ __launch_bounds__(256) void k_gemm(
    const float* __restrict__ x,
    const unsigned short* __restrict__ Bfrag_g,
    const float* __restrict__ g_b,
    const float* __restrict__ ta_w, const float* __restrict__ pb_w,
    const float* __restrict__ biases,
    unsigned short* __restrict__ gxg,
    float* __restrict__ a_out, float* __restrict__ bsc_out)
{
    __shared__ float xs[CH][36];              // 36.9 KB (float4-aligned rows)
    __shared__ unsigned short xsb[32 * 264];  // 16.5 KB bf16 transposed tile
    __shared__ float ra[8][32], rp[8][32];    // 2 KB
    unsigned short* gout = (unsigned short*)&xs[0][0];  // reuse dead xs (8.5 KB need)

    const int b  = blockIdx.y;
    const int n0 = blockIdx.x * 32;
    const int tid = threadIdx.x;

    for (int t = tid; t < CH * 8; t += 256) {
        int c = t >> 3, n4 = t & 7;
        const float4* src = (const float4*)(x + ((size_t)b * CH + c) * NPIX + n0);
        *((float4*)&xs[c][n4 * 4]) = src[n4];
    }
    __syncthreads();

    const int p = tid & 31;        // pixel
    const int g = tid >> 5;        // channel group of 32

    // a/bsc partial dots (fp32 for rank accuracy)
    {
        float aa = 0.f, pp = 0.f;
#pragma unroll 8
        for (int cc = 0; cc < 32; ++cc) {
            int c = g * 32 + cc;
            float v = xs[c][p];
            aa += ta_w[c] * v;
            pp += pb_w[c] * v;
        }
        ra[g][p] = aa; rp[g][p] = pp;
    }
    // bf16 transpose into xsb[pixel][channel]
    {
        const int cbase = g * 32;
        unsigned int* dst = (unsigned int*)&xsb[p * 264 + cbase];
#pragma unroll
        for (int q = 0; q < 16; ++q) {
            float lo = xs[cbase + 2 * q][p];
            float hi = xs[cbase + 2 * q + 1][p];
            dst[q] = (unsigned int)f2bf(lo) | ((unsigned int)f2bf(hi) << 16);
        }
    }
    __syncthreads();

    if (tid < 32) {
        float sa = 0.f, sp = 0.f;
#pragma unroll
        for (int gg = 0; gg < 8; ++gg) { sa += ra[gg][tid]; sp += rp[gg][tid]; }
        a_out[b * NPIX + n0 + tid]   = sa + biases[0];
        bsc_out[b * NPIX + n0 + tid] = sp + biases[1];
    }

    // MFMA: D[px(32) x o(128)] = xsb(32x256) * g_wT(256x128)
    const int w = tid >> 6, l = tid & 63, lm = l & 15, lq = l >> 4;
    f32x4 acc[2][2];
#pragma unroll
    for (int mi = 0; mi < 2; ++mi)
#pragma unroll
        for (int ni = 0; ni < 2; ++ni) acc[mi][ni] = (f32x4){0.f, 0.f, 0.f, 0.f};

#pragma unroll
    for (int ks = 0; ks < 8; ++ks) {
        bf16x8 a0 = *(const bf16x8*)&xsb[lm * 264 + ks * 32 + lq * 8];
        bf16x8 a1 = *(const bf16x8*)&xsb[(16 + lm) * 264 + ks * 32 + lq * 8];
        bf16x8 b0 = *(const bf16x8*)(Bfrag_g + ((size_t)(ks * 8 + w * 2) * 64 + l) * 8);
        bf16x8 b1 = *(const bf16x8*)(Bfrag_g + ((size_t)(ks * 8 + w * 2 + 1) * 64 + l) * 8);
        acc[0][0] = __builtin_amdgcn_mfma_f32_16x16x32_bf16(a0, b0, acc[0][0], 0, 0, 0);
        acc[0][1] = __builtin_amdgcn_mfma_f32_16x16x32_bf16(a0, b1, acc[0][1], 0, 0, 0);
        acc[1][0] = __builtin_amdgcn_mfma_f32_16x16x32_bf16(a1, b0, acc[1][0], 0, 0, 0);
        acc[1][1] = __builtin_amdgcn_mfma_f32_16x16x32_bf16(a1, b1, acc[1][1], 0, 0, 0);
    }
    __syncthreads();   // xs reads all done; gout (aliased) safe to write

#pragma unroll
    for (int mi = 0; mi < 2; ++mi)
#pragma unroll
        for (int ni = 0; ni < 2; ++ni) {
            int o = w * 32 + ni * 16 + lm;
            float gb = g_b[o];
#pragma unroll
            for (int r = 0; r < 4; ++r) {
                int m = mi * 16 + lq * 4 + r;
                gout[m * 136 + o] = f2bf(acc[mi][ni][r] + gb);
            }
        }
    __syncthreads();

    {
        const int n = tid >> 3, ch = tid & 7;
        const uint4* s = (const uint4*)&gout[n * 136 + ch * 16];
        uint4* d = (uint4*)(gxg + ((size_t)(b * NPIX + n0 + n)) * CI + ch * 16);
        d[0] = s[0]; d[1] = s[1];
    }
}

// ---------------------------------------------------------------------------
// K3: per-batch bucket scatter: min/max -> 4096-bucket histogram -> scan ->
// scatter. Outputs grouped values s_sorted, forward map idx_sorted
// (rank -> pixel), bucket start table, (bmin, scale). grid (B), block 1024.
// ---------------------------------------------------------------------------
__global__ __launch_bounds__(1024) void k_bucketsort(
    const float* __restrict__ bsc,
    float* __restrict__ s_sorted, int* __restrict__ idx_sorted,
    int* __restrict__ bstart, float* __restrict__ params)
{
    __shared__ float vals[NPIX];
    __shared__ unsigned short qarr[NPIX];
    __shared__ int hist[NB];
    __shared__ int cnt[NB];
    __shared__ float red[1024];
    __shared__ float red2[1024];
    __shared__ float sh_min, sh_scale;

    const int b = blockIdx.x, tid = threadIdx.x;

    float lmin = FLT_MAX, lmax = -FLT_MAX;
    for (int i = tid; i < NPIX; i += 1024) {
        float v = bsc[b * NPIX + i];
        vals[i] = v;
        lmin = fminf(lmin, v);
        lmax = fmaxf(lmax, v);
    }
    red[tid] = lmin; red2[tid] = lmax;
    __syncthreads();
    for (int off = 512; off > 0; off >>= 1) {
        if (tid < off) {
            red[tid]  = fminf(red[tid],  red[tid + off]);
            red2[tid] = fmaxf(red2[tid], red2[tid + off]);
        }
        __syncthreads();
    }
    if (tid == 0) {
        float mn = red[0], mx = red2[0];
        float range = mx - mn;
        float scale = (range > 0.f) ? (float)NB / range : 0.f;
        sh_min = mn; sh_scale = scale;
        params[b * 2] = mn; params[b * 2 + 1] = scale;
    }
    for (int i = tid; i < NB; i += 1024) { hist[i] = 0; cnt[i] = 0; }
    __syncthreads();

    const float bmin = sh_min, scale = sh_scale;
    for (int i = tid; i < NPIX; i += 1024) {
        int q = (int)((vals[i] - bmin) * scale);
        q = (q < 0) ? 0 : ((q > NB - 1) ? NB - 1 : q);
        qarr[i] = (unsigned short)q;
        atomicAdd(&hist[q], 1);
    }
    __syncthreads();

    int* psum = (int*)red;
    const int base4 = tid * 4;
    int h0 = hist[base4], h1 = hist[base4 + 1], h2 = hist[base4 + 2], h3 = hist[base4 + 3];
    psum[tid] = h0 + h1 + h2 + h3;
    __syncthreads();
    for (int off = 1; off < 1024; off <<= 1) {
        int v = psum[tid];
        int w = (tid >= off) ? psum[tid - off] : 0;
        __syncthreads();
        psum[tid] = v + w;
        __syncthreads();
    }
    int excl = (tid == 0) ? 0 : psum[tid - 1];
    hist[base4]     = excl;
    hist[base4 + 1] = excl + h0;
    hist[base4 + 2] = excl + h0 + h1;
    hist[base4 + 3] = excl + h0 + h1 + h2;
    __syncthreads();

    for (int i = tid; i < NB; i += 1024) bstart[b * (NB + 1) + i] = hist[i];
    if (tid == 0) bstart[b * (NB + 1) + NB] = NPIX;

    for (int i = tid; i < NPIX; i += 1024) {
        int q = qarr[i];
        int pos = hist[q] + atomicAdd(&cnt[q], 1);
        s_sorted[b * NPIX + pos]   = vals[i];
        idx_sorted[b * NPIX + pos] = i;
    }
}

// ---------------------------------------------------------------------------
// K4: per-chunk sums, single gather via idx_sorted (staged in LDS).
// grid (NCHUNK, B), block 128.
// ---------------------------------------------------------------------------
__global__ __launch_bounds__(128) void k_csum(
    const unsigned short* __restrict__ gxg,
    const float* __restrict__ s_sorted, const int* __restrict__ idx_sorted,
    float* __restrict__ CS1, float* __restrict__ CS2)
{
    __shared__ int   sidx[32];
    __shared__ float sval[32];
    const int b = blockIdx.y, c = blockIdx.x, o = threadIdx.x;
    const int base = b * NPIX + c * 32;
    if (o < 32) {
        sidx[o] = idx_sorted[base + o];
        sval[o] = s_sorted[base + o];
    }
    __syncthreads();

    float a1 = 0.f, a2 = 0.f;
#pragma unroll 8
    for (int rr = 0; rr < 32; ++rr) {
        float v = bf2f(gxg[((size_t)(b * NPIX + sidx[rr])) * CI + o]);
        a1 += v;
        a2 += sval[rr] * v;
    }
    CS1[(b * 100 + c) * CI + o] = a1;
    CS2[(b * 100 + c) * CI + o] = a2;
}

// ---------------------------------------------------------------------------
// K5: suffix scan over 98 chunks, LDS-staged. grid (B, 2): y=0 -> CS1,
// y=1 -> CS2. Zeroes rows 98/99. block 128.
// ---------------------------------------------------------------------------
__global__ __launch_bounds__(128) void k_suffix(
    float* __restrict__ CS1, float* __restrict__ CS2)
{
    __shared__ float buf[NCHUNK * CI];   // 49 KB
    const int b = blockIdx.x, tid = threadIdx.x;
    float* __restrict__ CS = blockIdx.y ? CS2 : CS1;

    for (int i = tid; i < NCHUNK * CI; i += 128) buf[i] = CS[b * 100 * CI + i];
    __syncthreads();
    {
        float acc = 0.f;
        for (int c = NCHUNK - 1; c >= 0; --c) {
            acc += buf[c * CI + tid];
            buf[c * CI + tid] = acc;
        }
    }
    __syncthreads();
    for (int i = tid; i < NCHUNK * CI; i += 128) CS[b * 100 * CI + i] = buf[i];
    CS[(b * 100 + 98) * CI + tid] = 0.f;
    CS[(b * 100 + 99) * CI + tid] = 0.f;
}

// ---------------------------------------------------------------------------
// K6 (fused): bucket lookup -> chunk-rounded rank -> y row from L2-resident
// CS tables -> MFMA wz-GEMM -> BN -> residual -> out. grid (98, B), blk 256.
// ---------------------------------------------------------------------------
__global__ __launch_bounds__(256) void k_final(
    const float* __restrict__ x,
    const float* __restrict__ a_arr, const float* __restrict__ wf_b,
    const float* __restrict__ CS1, const float* __restrict__ CS2,
    const int* __restrict__ bstart, const float* __restrict__ params,
    const unsigned short* __restrict__ Bfrag_w,
    const float* __restrict__ wz_b,
    const float* __restrict__ bn_g, const float* __restrict__ bn_b,
    const float* __restrict__ bn_m, const float* __restrict__ bn_v,
    float* __restrict__ out)
{
    __shared__ unsigned short ys[32 * 136];  // bf16 y tile, pad 136
    __shared__ float Df[32 * 260];           // fp32 D tile, pad 260
    __shared__ int   rs[32];
    __shared__ float ts[32];

    const int b = blockIdx.y;
    const int n0 = blockIdx.x * 32;
    const int tid = threadIdx.x;

    if (tid < 32) {
        float t = a_arr[b * NPIX + n0 + tid] + wf_b[0];
        float bmin = params[b * 2], scale = params[b * 2 + 1];
        float fq = (-t - bmin) * scale;
        int kb = (int)(fq + 0.5f);
        kb = (kb < 0) ? 0 : ((kb > NB) ? NB : kb);
        int r = bstart[b * (NB + 1) + kb];
        int cstar = (r + 16) >> 5;           // nearest chunk boundary, 0..98
        cstar = (cstar > 98) ? 98 : cstar;
        rs[tid] = cstar;
        ts[tid] = t;
    }
    __syncthreads();

    const int o = tid & 127;
    const int h = tid >> 7;
    const float invN = 1.0f / (float)NPIX;

#pragma unroll 4
    for (int i = 0; i < 16; ++i) {
        int n = h * 16 + i;
        int cb = (b * 100 + rs[n]) * CI + o;
        float S1 = CS1[cb], S2 = CS2[cb];
        ys[n * 136 + o] = f2bf((ts[n] * S1 + S2) * invN);
    }
    __syncthreads();

    // MFMA: D[px(32) x cc(256)] = ys(32x128) * wz_wT(128x256)
    const int w = tid >> 6, l = tid & 63, lm = l & 15, lq = l >> 4;
    f32x4 acc[2][4];
#pragma unroll
    for (int mi = 0; mi < 2; ++mi)
#pragma unroll
        for (int ni = 0; ni < 4; ++ni) acc[mi][ni] = (f32x4){0.f, 0.f, 0.f, 0.f};

#pragma unroll
    for (int ks = 0; ks < 4; ++ks) {
        bf16x8 a0 = *(const bf16x8*)&ys[lm * 136 + ks * 32 + lq * 8];
        bf16x8 a1 = *(const bf16x8*)&ys[(16 + lm) * 136 + ks * 32 + lq * 8];
#pragma unroll
        for (int ni = 0; ni < 4; ++ni) {
            bf16x8 bb = *(const bf16x8*)(Bfrag_w + ((size_t)(ks * 16 + w * 4 + ni) * 64 + l) * 8);
            acc[0][ni] = __builtin_amdgcn_mfma_f32_16x16x32_bf16(a0, bb, acc[0][ni], 0, 0, 0);
            acc[1][ni] = __builtin_amdgcn_mfma_f32_16x16x32_bf16(a1, bb, acc[1][ni], 0, 0, 0);
        }
    }

#pragma unroll
    for (int mi = 0; mi < 2; ++mi)
#pragma unroll
        for (int ni = 0; ni < 4; ++ni) {
            int cc = w * 64 + ni * 16 + lm;
#pragma unroll
            for (int r = 0; r < 4; ++r) {
                int m = mi * 16 + lq * 4 + r;
                Df[m * 260 + cc] = acc[mi][ni][r];
            }
        }
    __syncthreads();

    // epilogue: one thread per output channel
    const int cc = tid;
    const float inv  = bn_g[cc] * rsqrtf(bn_v[cc] + BN_EPS);
    const float bias = (wz_b[cc] - bn_m[cc]) * inv + bn_b[cc];

    const float4* xp = (const float4*)(x   + ((size_t)b * CH + cc) * NPIX + n0);
    float4*       op = (float4*)      (out + ((size_t)b * CH + cc) * NPIX + n0);
#pragma unroll
    for (int n4 = 0; n4 < 8; ++n4) {
        float4 xv = xp[n4];
        float4 ov;
        ov.x = Df[(n4 * 4 + 0) * 260 + cc] * inv + bias + xv.x;
        ov.y = Df[(n4 * 4 + 1) * 260 + cc] * inv + bias + xv.y;
        ov.z = Df[(n4 * 4 + 2) * 260 + cc] * inv + bias + xv.z;
        ov.w = Df[(n4 * 4 + 3) * 260 + cc] * inv + bias + xv.w;
        op[n4] = ov;
    }
}

// ---------------------------------------------------------------------------
extern "C" void kernel_launch(void* const* d_in, const int* in_sizes, int n_in,
                              void* d_out, int out_size, void* d_ws, size_t ws_size,
                              hipStream_t stream)
{
    const float* x       = (const float*)d_in[0];
    const float* g_w     = (const float*)d_in[1];
    const float* g_b     = (const float*)d_in[2];
    const float* theta_w = (const float*)d_in[3];
    const float* theta_b = (const float*)d_in[4];
    const float* phi_w   = (const float*)d_in[5];
    const float* phi_b   = (const float*)d_in[6];
    const float* wf_w    = (const float*)d_in[7];
    const float* wf_b    = (const float*)d_in[8];
    const float* wz_w    = (const float*)d_in[9];
    const float* wz_b    = (const float*)d_in[10];
    const float* bn_g    = (const float*)d_in[11];
    const float* bn_b    = (const float*)d_in[12];
    const float* bn_m    = (const float*)d_in[13];
    const float* bn_v    = (const float*)d_in[14];

    float* ws = (float*)d_ws;
    float* ta_w   = ws;                                    // 256
    float* pb_w   = ws + 256;                              // 256
    float* biases = ws + 512;                              // 4
    float* params = ws + 516;                              // 16
    float* a_arr  = ws + 532;                              // 25088
    float* bsc      = a_arr + BATCH * NPIX;                // 25088
    float* s_sorted = bsc + BATCH * NPIX;                  // 25088
    int*   idx_sorted = (int*)(s_sorted + BATCH * NPIX);   // 25088
    int*   bstart   = idx_sorted + BATCH * NPIX;           // 8*4097
    float* CS1    = (float*)(bstart + BATCH * (NB + 1));   // 102400
    float* CS2    = CS1 + BATCH * 100 * CI;                // 102400
    unsigned short* Bfrag_g = (unsigned short*)(CS2 + BATCH * 100 * CI); // 32768
    unsigned short* Bfrag_w = Bfrag_g + 32768;             // 32768
    unsigned short* gxg = Bfrag_w + 32768;                 // 8*3136*128 bf16

    k_fold<<<17, 256, 0, stream>>>(wf_w, theta_w, theta_b, phi_w, phi_b,
                                   g_w, wz_w, ta_w, pb_w, biases,
                                   Bfrag_g, Bfrag_w);

    k_gemm<<<dim3(NCHUNK, BATCH), 256, 0, stream>>>(
        x, Bfrag_g, g_b, ta_w, pb_w, biases, gxg, a_arr, bsc);

    k_bucketsort<<<BATCH, 1024, 0, stream>>>(bsc, s_sorted, idx_sorted,
                                             bstart, params);

    k_csum<<<dim3(NCHUNK, BATCH), 128, 0, stream>>>(
        gxg, s_sorted, idx_sorted, CS1, CS2);

    k_suffix<<<dim3(BATCH, 2), 128, 0, stream>>>(CS1, CS2);

    k_final<<<dim3(NCHUNK, BATCH), 256, 0, stream>>>(
        x, a_arr, wf_b, CS1, CS2, bstart, params, Bfrag_w,
        wz_b, bn_g, bn_b, bn_m, bn_v, (float*)d_out);
}